// Round 9
// baseline (738.996 us; speedup 1.0000x reference)
//
#include <hip/hip_runtime.h>
#include <cstddef>

#define H 128

typedef unsigned short ushort_t;
typedef unsigned char uchar_t;
typedef __attribute__((ext_vector_type(8))) short short8;
typedef __attribute__((ext_vector_type(4))) float floatx4;
typedef __attribute__((ext_vector_type(2))) float floatx2;

// ---------------- helpers ----------------
__device__ __forceinline__ unsigned fkey(float f){
    unsigned u = __float_as_uint(f);
    return (u & 0x80000000u) ? ~u : (u | 0x80000000u);
}
__device__ __forceinline__ float funkey(unsigned k){
    unsigned u = (k & 0x80000000u) ? (k ^ 0x80000000u) : ~k;
    return __uint_as_float(u);
}
__device__ __forceinline__ ushort_t f2bf(float f){
    unsigned u = __float_as_uint(f);
    u += 0x7fffu + ((u >> 16) & 1u);      // round-to-nearest-even
    return (ushort_t)(u >> 16);
}
__device__ __forceinline__ float bf2f(ushort_t h){
    return __uint_as_float(((unsigned)h) << 16);
}
__device__ __forceinline__ uchar_t f2fp8(float v){
    int p = __builtin_amdgcn_cvt_pk_fp8_f32(v, v, 0, false);
    return (uchar_t)(p & 0xff);
}
// async global -> LDS, 16B per lane. LDS dest = wave-uniform base + lane*16.
__device__ __forceinline__ void gll16(const void* g, void* l){
    __builtin_amdgcn_global_load_lds(
        (const __attribute__((address_space(1))) unsigned int*)g,
        (__attribute__((address_space(3))) unsigned int*)l, 16, 0, 0);
}
// accumulate 8 fp8 (one int2) into 8 fp32 with weight
__device__ __forceinline__ void acc8f8(float* a, int2 u, float w){
    floatx2 p;
    p = __builtin_amdgcn_cvt_pk_f32_fp8(u.x, false); a[0] += w*p.x; a[1] += w*p.y;
    p = __builtin_amdgcn_cvt_pk_f32_fp8(u.x, true);  a[2] += w*p.x; a[3] += w*p.y;
    p = __builtin_amdgcn_cvt_pk_f32_fp8(u.y, false); a[4] += w*p.x; a[5] += w*p.y;
    p = __builtin_amdgcn_cvt_pk_f32_fp8(u.y, true);  a[6] += w*p.x; a[7] += w*p.y;
}

// ---------------- fused embeddings (bf16 states + fp8 shadows) ---------------
// blocks [0, nbP): place side; rest: trans side.
__global__ __launch_bounds__(256) void k_embed2(
    const float* __restrict__ pf, const float* __restrict__ Wpe,
    const float* __restrict__ bpe,
    const float* __restrict__ tf, const float* __restrict__ Wte,
    const float* __restrict__ bte,
    ushort_t* __restrict__ outP, uchar_t* __restrict__ xP,
    ushort_t* __restrict__ outT, uchar_t* __restrict__ xT,
    int P, int T, int nbP)
{
    int tid = threadIdx.x;
    if ((int)blockIdx.x < nbP){
        int idx = blockIdx.x*256 + tid;
        if (idx >= P*32) return;
        int p = idx >> 5, q = (idx & 31) << 2;
        float v = pf[p];
        float4 w = *(const float4*)(Wpe + q);
        float4 b = *(const float4*)(bpe + q);
        float v0 = v*w.x + b.x, v1 = v*w.y + b.y, v2 = v*w.z + b.z, v3 = v*w.w + b.w;
        ushort4 o;
        o.x = f2bf(v0); o.y = f2bf(v1); o.z = f2bf(v2); o.w = f2bf(v3);
        *(ushort4*)(outP + (size_t)p*H + q) = o;
        int pk = __builtin_amdgcn_cvt_pk_fp8_f32(v0, v1, 0, false);
        pk = __builtin_amdgcn_cvt_pk_fp8_f32(v2, v3, pk, true);
        *(int*)(xP + (size_t)p*H + q) = pk;
    } else {
        __shared__ float Wl[8*H];
        __shared__ float Bl[H];
        #pragma unroll
        for (int t = 0; t < 4; t++) Wl[tid + t*256] = Wte[tid + t*256];
        if (tid < H) Bl[tid] = bte[tid];
        __syncthreads();
        int idx = (blockIdx.x - nbP)*256 + tid;
        if (idx >= T*32) return;
        int t = idx >> 5, q = (idx & 31) << 2;
        float4 acc = *(float4*)(&Bl[q]);
        #pragma unroll
        for (int k = 0; k < 8; k++){
            float s = tf[(size_t)t*8 + k];
            float4 w = *(float4*)(&Wl[k*H + q]);
            acc.x += s*w.x; acc.y += s*w.y; acc.z += s*w.z; acc.w += s*w.w;
        }
        ushort4 o;
        o.x = f2bf(acc.x); o.y = f2bf(acc.y); o.z = f2bf(acc.z); o.w = f2bf(acc.w);
        *(ushort4*)(outT + (size_t)t*H + q) = o;
        int pk = __builtin_amdgcn_cvt_pk_fp8_f32(acc.x, acc.y, 0, false);
        pk = __builtin_amdgcn_cvt_pk_fp8_f32(acc.z, acc.w, pk, true);
        *(int*)(xT + (size_t)t*H + q) = pk;
    }
}

// prefix embedding + zero mean shadow copies + softmax slots + Sp shards
__global__ void k_init_small(const float* __restrict__ pe, int plen,
                             const float* __restrict__ Wpr, const float* __restrict__ bpr,
                             float* __restrict__ prefix, float* __restrict__ meanPsh,
                             float* __restrict__ meanTsh, float* __restrict__ slots,
                             float* __restrict__ SpSh)
{
    int c = threadIdx.x;  // 128 threads
    float a = bpr[c];
    for (int k = 0; k < plen; k++) a += pe[k]*Wpr[k*H + c];
    prefix[c] = a;
    for (int i = c; i < 4096; i += 128){ meanPsh[i] = 0.f; meanTsh[i] = 0.f; }
    for (int i = c; i < 192; i += 128) SpSh[i] = 0.f;
    if (c < 16) slots[c] = 0.f;   // fkey-space 0 == -inf
}

// ---------------- combined weight prep: A1-half + folded Wc ------------------
__global__ __launch_bounds__(256) void k_wprep2(
    const float* __restrict__ p2t_W, const float* __restrict__ t2p_W,
    const float* __restrict__ tu_W,  const float* __restrict__ pu_W,
    ushort_t* __restrict__ WT, int total)   // total = L*32768
{
    int e = blockIdx.x*256 + threadIdx.x;
    if (e >= total) return;
    int l = e / 32768, oo = e - l*32768;
    int side = oo >> 14, o2 = oo & 16383;
    int n = o2 >> 7, k = o2 & 127;
    const float* A  = side ? (t2p_W + (size_t)l*16384) : (p2t_W + (size_t)l*16384);
    const float* Bm = side ? (pu_W  + (size_t)l*32768) : (tu_W  + (size_t)l*32768);
    ushort_t* dst = WT + (size_t)l*65536 + (size_t)side*32768 + n*256;
    dst[k] = f2bf(Bm[(size_t)k*H + n]);                  // Wtop half
    const float* Ar = A + (size_t)k*H;
    const float* Bc = Bm + (size_t)128*H + n;
    float s = 0.f;
    #pragma unroll 4
    for (int j = 0; j < 128; j++) s += Ar[j] * Bc[(size_t)j*H];
    dst[128 + k] = f2bf(s);                              // folded Wc half
}

// ---------------- folded small vectors: wv, bc, c0 ---------------------------
__global__ __launch_bounds__(128) void k_wsmall(
    const float* __restrict__ p2t_W, const float* __restrict__ t2p_W,
    const float* __restrict__ tu_W,  const float* __restrict__ pu_W,
    const float* __restrict__ p2t_b, const float* __restrict__ t2p_b,
    const float* __restrict__ ta_W,  const float* __restrict__ ta_b,
    const float* __restrict__ pa_W,  const float* __restrict__ pa_b,
    float* __restrict__ wv, float* __restrict__ c0v, float* __restrict__ bcv)
{
    int b = blockIdx.x, l = b >> 1, side = b & 1;
    const float* A  = side ? (t2p_W + (size_t)l*16384) : (p2t_W + (size_t)l*16384);
    const float* Bm = side ? (pu_W  + (size_t)l*32768) : (tu_W  + (size_t)l*32768);
    const float* ab = side ? (t2p_b + (size_t)l*H) : (p2t_b + (size_t)l*H);
    const float* av = side ? (pa_W  + (size_t)l*H) : (ta_W  + (size_t)l*H);
    float asc       = side ? pa_b[l] : ta_b[l];
    int tid = threadIdx.x;
    int o = (l*2 + side)*H;
    float s = 0.f;
    for (int n = 0; n < 128; n++) s += A[(size_t)tid*H + n] * av[n];
    wv[o + tid] = s;
    float s2 = 0.f;
    for (int j = 0; j < 128; j++) s2 += ab[j] * Bm[(size_t)(128+j)*H + tid];
    bcv[o + tid] = s2;
    if (tid == 0){
        float c = 0.f;
        for (int n = 0; n < 128; n++) c += ab[n]*av[n];
        c0v[l*2 + side] = c + asc;
    }
}

// ---------------- CSR build ----------------
__global__ __launch_bounds__(256) void k_zero_ints(int* __restrict__ p, int n)
{
    int i = blockIdx.x*256 + threadIdx.x;
    int stride = gridDim.x*256;
    for (; i < n; i += stride) p[i] = 0;
}

__global__ __launch_bounds__(256) void k_hist2(
    const int* __restrict__ preD, const int* __restrict__ postD, int E,
    int* __restrict__ cntPre, int* __restrict__ cntPost,
    int* __restrict__ rankPre, int* __restrict__ rankPost)
{
    int i = blockIdx.x*256 + threadIdx.x;
    int stride = gridDim.x*256;
    for (; i < E; i += stride){
        rankPre[i] = atomicAdd(&cntPre[preD[i]], 1);
        rankPost[i] = atomicAdd(&cntPost[postD[i]], 1);
    }
}

__global__ __launch_bounds__(256) void k_scan_part(
    const int* __restrict__ cnt, int N, int* __restrict__ bsum)
{
    __shared__ int wsum[4];
    int tid = threadIdx.x, lane = tid & 63, wid = tid >> 6;
    int base = blockIdx.x*1024 + tid*4;
    int4 v = make_int4(0,0,0,0);
    if (base + 3 < N) v = *(const int4*)(cnt + base);
    else {
        if (base+0 < N) v.x = cnt[base+0];
        if (base+1 < N) v.y = cnt[base+1];
        if (base+2 < N) v.z = cnt[base+2];
    }
    int s = v.x + v.y + v.z + v.w;
    #pragma unroll
    for (int o = 1; o < 64; o <<= 1) s += __shfl_xor(s, o);
    if (lane == 0) wsum[wid] = s;
    __syncthreads();
    if (tid == 0) bsum[blockIdx.x] = wsum[0] + wsum[1] + wsum[2] + wsum[3];
}

__global__ __launch_bounds__(256) void k_scan_bsum(int* __restrict__ bsum, int nb)
{
    __shared__ int wsum[4];
    int tid = threadIdx.x, lane = tid & 63, wid = tid >> 6;
    int x = (tid < nb) ? bsum[tid] : 0;
    int inc = x;
    #pragma unroll
    for (int o = 1; o < 64; o <<= 1){
        int u = __shfl_up(inc, o);
        if (lane >= o) inc += u;
    }
    if (lane == 63) wsum[wid] = inc;
    __syncthreads();
    int woff = 0;
    if (wid > 0) woff += wsum[0];
    if (wid > 1) woff += wsum[1];
    if (wid > 2) woff += wsum[2];
    if (tid < nb) bsum[tid] = woff + inc - x;
}

__global__ __launch_bounds__(256) void k_scan_final(
    const int* __restrict__ cnt, int N, const int* __restrict__ bsum,
    int* __restrict__ rp, int E)
{
    __shared__ int wsum[4];
    int tid = threadIdx.x, lane = tid & 63, wid = tid >> 6;
    int base = blockIdx.x*1024 + tid*4;
    int4 v = make_int4(0,0,0,0);
    if (base + 3 < N) v = *(const int4*)(cnt + base);
    else {
        if (base+0 < N) v.x = cnt[base+0];
        if (base+1 < N) v.y = cnt[base+1];
        if (base+2 < N) v.z = cnt[base+2];
    }
    int t0 = v.x, t1 = t0 + v.y, t2 = t1 + v.z, t3 = t2 + v.w;
    int inc = t3;
    #pragma unroll
    for (int o = 1; o < 64; o <<= 1){
        int u = __shfl_up(inc, o);
        if (lane >= o) inc += u;
    }
    if (lane == 63) wsum[wid] = inc;
    __syncthreads();
    int woff = 0;
    if (wid > 0) woff += wsum[0];
    if (wid > 1) woff += wsum[1];
    if (wid > 2) woff += wsum[2];
    int off = bsum[blockIdx.x] + woff + inc - t3;
    if (base+0 < N) rp[base+0] = off;
    if (base+1 < N) rp[base+1] = off + t0;
    if (base+2 < N) rp[base+2] = off + t1;
    if (base+3 < N) rp[base+3] = off + t2;
    if (blockIdx.x == 0 && tid == 0) rp[N] = E;
}

__global__ __launch_bounds__(256) void k_fill2(
    const int* __restrict__ preS, const int* __restrict__ preD,
    const int* __restrict__ postS, const int* __restrict__ postD, int E,
    const int* __restrict__ rpPre, const int* __restrict__ rankPre, int* __restrict__ csrPre,
    const int* __restrict__ rpPost, const int* __restrict__ rankPost, int* __restrict__ csrPost)
{
    int i = blockIdx.x*256 + threadIdx.x;
    int stride = gridDim.x*256;
    for (; i < E; i += stride){
        csrPre[rpPre[preD[i]] + rankPre[i]] = preS[i];
        csrPost[rpPost[postD[i]] + rankPost[i]] = postS[i];
    }
}

// ---------------- dual-side score GEMV: y[r] = h[r].wv + c0, fused max -------
__global__ __launch_bounds__(256) void k_gemv2(
    const ushort_t* __restrict__ Ap, int P,
    const ushort_t* __restrict__ At, int T,
    const float* __restrict__ wvA, const float* __restrict__ wvB,
    const float* __restrict__ c0v, int c0iA, int c0iB,
    float* __restrict__ yA, float* __restrict__ yB,
    unsigned* __restrict__ MkA, unsigned* __restrict__ MkB)
{
    __shared__ float wm[4];
    int half = gridDim.x >> 1;
    int side = (blockIdx.x >= half);
    const ushort_t* A = side ? At : Ap;
    int M = side ? T : P;
    const float* wv = side ? wvB : wvA;
    float c0 = c0v[side ? c0iB : c0iA];
    float* y = side ? yB : yA;
    unsigned* Mk = side ? MkB : MkA;
    int b = side ? (blockIdx.x - half) : blockIdx.x;

    int tid = threadIdx.x, lane = tid & 63, wid = tid >> 6;
    int g = tid >> 4, gl = tid & 15;
    float w8[8];
    #pragma unroll
    for (int i = 0; i < 8; i++) w8[i] = wv[gl*8 + i];
    int stride = half*16;
    float lmax = -3.402823466e38f;
    for (int r = b*16 + g; r < M; r += stride){
        short8 u = *(const short8*)(A + (size_t)r*H + gl*8);
        float s = 0.f;
        #pragma unroll
        for (int i = 0; i < 8; i++) s += bf2f((ushort_t)u[i]) * w8[i];
        s += __shfl_xor(s, 1); s += __shfl_xor(s, 2);
        s += __shfl_xor(s, 4); s += __shfl_xor(s, 8);
        s += c0;
        if (gl == 0) y[r] = s;
        lmax = fmaxf(lmax, s);
    }
    #pragma unroll
    for (int o = 1; o < 64; o <<= 1) lmax = fmaxf(lmax, __shfl_xor(lmax, o));
    if (lane == 0) wm[wid] = lmax;
    __syncthreads();
    if (tid == 0){
        float m = fmaxf(fmaxf(wm[0], wm[1]), fmaxf(wm[2], wm[3]));
        atomicMax(Mk, fkey(m));
    }
}

// ---------------- dual-side CSR gather: inline exp + sharded Sp --------------
// G[r] = sum_e exp(y[src]-M) * X[src] (UNNORMALIZED); sdeg[r] = sum exp;
// SpShl[side*32 + bid&31] += block sum (32-way sharded; R6 atomic lesson).
__global__ __launch_bounds__(256) void k_gather2(
    const int* __restrict__ rpPre, const int* __restrict__ csrPre, int T,
    const int* __restrict__ rpPost, const int* __restrict__ csrPost, int P,
    const float* __restrict__ yA, const float* __restrict__ yB,
    const unsigned* __restrict__ MkA, const unsigned* __restrict__ MkB,
    const uchar_t* __restrict__ XP, const uchar_t* __restrict__ XT,
    ushort_t* __restrict__ GbA, ushort_t* __restrict__ GbB,
    float* __restrict__ sdegA, float* __restrict__ sdegB,
    float* __restrict__ SpShl)
{
    __shared__ float sseh[16];
    int nbT = (T + 15) >> 4;
    int side = (blockIdx.x >= nbT);
    const int* rp   = side ? rpPost : rpPre;
    const int* csr  = side ? csrPost : csrPre;
    const float* y  = side ? yB : yA;
    float Mv = funkey((side ? MkB : MkA)[0]);
    const uchar_t* X = side ? XT : XP;
    ushort_t* G     = side ? GbB : GbA;
    float* sdeg     = side ? sdegB : sdegA;
    int Nrow        = side ? P : T;
    int b = side ? (blockIdx.x - nbT) : blockIdx.x;

    int tid = threadIdx.x;
    int g = tid >> 4, gl = tid & 15;          // 16 groups x 16 lanes
    int r = b*16 + g;
    bool active = (r < Nrow);
    float se = 0.f;
    if (active){
        int j0 = rp[r], j1 = rp[r+1];
        const int2* X8 = (const int2*)X;      // fp8 row = 16 int2 (128 fp8)
        float a[8] = {0.f,0.f,0.f,0.f,0.f,0.f,0.f,0.f};
        int j = j0;
        for (; j + 1 < j1; j += 2){
            int s0 = csr[j], s1 = csr[j+1];
            float e0 = expf(y[s0] - Mv);
            float e1 = expf(y[s1] - Mv);
            int2 u0 = X8[(size_t)s0*16 + gl];
            int2 u1 = X8[(size_t)s1*16 + gl];
            se += e0 + e1;
            acc8f8(a, u0, e0);
            acc8f8(a, u1, e1);
        }
        if (j < j1){
            int s0 = csr[j];
            float e0 = expf(y[s0] - Mv);
            int2 u0 = X8[(size_t)s0*16 + gl];
            se += e0;
            acc8f8(a, u0, e0);
        }
        int4 o;
        o.x = (int)((((unsigned)f2bf(a[1])) << 16) | (unsigned)f2bf(a[0]));
        o.y = (int)((((unsigned)f2bf(a[3])) << 16) | (unsigned)f2bf(a[2]));
        o.z = (int)((((unsigned)f2bf(a[5])) << 16) | (unsigned)f2bf(a[4]));
        o.w = (int)((((unsigned)f2bf(a[7])) << 16) | (unsigned)f2bf(a[6]));
        ((int4*)G)[(size_t)r*16 + gl] = o;
        if (gl == 0) sdeg[r] = se;
    }
    if (gl == 0) sseh[g] = active ? se : 0.f;
    __syncthreads();
    if (tid == 0){
        float s = 0.f;
        #pragma unroll
        for (int i = 0; i < 16; i++) s += sseh[i];
        atomicAdd(&SpShl[side*32 + (blockIdx.x & 31)], s);
    }
}

// ---------------- dual-side update GEMM --------------------------------------
// out = relu(A1 + A1@Wtop + invS*(G@Wc + sdeg*bc) + b)   [IN-PLACE: out == A1]
// 3-buffer LDS ring (2-deep prefetch, counted vmcnt, raw s_barrier), XOR-
// swizzled via pre-swizzled global source. Residual A1 via identity-MFMA.
// invS = 1/sum(32 Sp shards). STORE vmcnt 19/17 (R7-validated: 1 sdeg + 16
// stores + 2 stage). STORE=false: colsum into 32 shadow copies; vmcnt 3/1.
template<bool STORE>
__global__ __launch_bounds__(256, 4) void k_up2(
    ushort_t* trans_h, ushort_t* place_h,
    const ushort_t* __restrict__ GbA, const ushort_t* __restrict__ GbB,
    const ushort_t* __restrict__ WTl,
    const float* __restrict__ tub, const float* __restrict__ pub,
    const float* __restrict__ bcA, const float* __restrict__ bcB,
    const float* __restrict__ SpShl,        // [64]: side0 0..31, side1 32..63
    const float* __restrict__ sdegA, const float* __restrict__ sdegB,
    uchar_t* __restrict__ XT, uchar_t* __restrict__ XP,
    int T, int P, int gridT, int gridP,
    float* __restrict__ meanTsh, float* __restrict__ meanPsh)
{
    __shared__ __align__(16) char As[3*8192];   // 3 x (A1 4KB | A2 4KB)
    __shared__ float csum[H];
    int side = (blockIdx.x >= gridT);
    ushort_t* A1        = side ? place_h : trans_h;
    const ushort_t* A2  = side ? GbB : GbA;
    const ushort_t* WT  = WTl + (side ? 32768 : 0);
    const float* bias   = side ? pub : tub;
    const float* bcp    = side ? bcB : bcA;
    const float* sdeg   = side ? sdegB : sdegA;
    uchar_t* outF8      = side ? XP : XT;
    int M               = side ? P : T;
    int G               = side ? gridP : gridT;
    int t0              = side ? (blockIdx.x - gridT) : blockIdx.x;
    float* colsum       = side ? meanPsh : meanTsh;
    float Sv = 0.f;
    {
        const float* sp = SpShl + (side ? 32 : 0);
        #pragma unroll
        for (int i = 0; i < 32; i++) Sv += sp[i];
    }
    float invS = 1.f / Sv;

    int tid = threadIdx.x;
    int lane = tid & 63, wid = tid >> 6;
    int quad = lane >> 4, l15 = lane & 15;
    int strip = wid*32;
    short8 bfr1[2][4], bfr2[2][4];
    float bcol[2], bc2[2];
    #pragma unroll
    for (int j = 0; j < 2; j++){
        int col = strip + j*16 + l15;
        #pragma unroll
        for (int kk = 0; kk < 4; kk++){
            bfr1[j][kk] = *(const short8*)(WT + (size_t)col*256 + kk*32 + quad*8);
            bfr2[j][kk] = *(const short8*)(WT + (size_t)col*256 + 128 + kk*32 + quad*8);
        }
        bcol[j] = bias[col];
        bc2[j]  = bcp[col];
    }
    // identity B-fragments: transpose the wave's A1 fragment window into C-layout
    short8 If0, If1;
    #pragma unroll
    for (int e = 0; e < 8; e++){
        int kloc = quad*8 + e;
        If0[e] = (kloc == l15)      ? (short)0x3F80 : (short)0;
        If1[e] = (kloc == l15 + 16) ? (short)0x3F80 : (short)0;
    }
    if constexpr (!STORE){ if (tid < H) csum[tid] = 0.f; }
    float cs[2] = {0.f, 0.f};

    int tiles = (M + 15) >> 4;
    if (t0 >= tiles) return;
    int srow = tid >> 4;
    int su = (tid & 15) ^ srow;
    const ushort_t* g1b = A1 + (size_t)srow*H + su*8;
    const ushort_t* g2b = A2 + (size_t)srow*H + su*8;
    char* AsB = As;

    #define STAGE_UP(bo, t) do { \
        gll16(g1b + (size_t)(t)*(16*H), AsB + (bo) + (wid<<10)); \
        gll16(g2b + (size_t)(t)*(16*H), AsB + (bo) + 4096 + (wid<<10)); \
    } while(0)

    STAGE_UP(0, t0);
    int t1p = t0 + G;
    if (t1p < tiles){
        STAGE_UP(8192, t1p);
        asm volatile("s_waitcnt vmcnt(2)\ns_barrier" ::: "memory");
    } else {
        asm volatile("s_waitcnt vmcnt(0)\ns_barrier" ::: "memory");
    }

    int t = t0, bo = 0;
    for (;;){
        const char* rb = AsB + bo;
        int row0 = t << 4;
        float4 sd4 = *(const float4*)(sdeg + row0 + quad*4);
        float sdv[4] = {sd4.x, sd4.y, sd4.z, sd4.w};
        short8 a1f[4], a2f[4];
        #pragma unroll
        for (int kk = 0; kk < 4; kk++){
            int sw = ((((kk<<2)+quad) ^ l15) << 4);
            a1f[kk] = *(const short8*)(rb + (l15<<8) + sw);
            a2f[kk] = *(const short8*)(rb + 4096 + (l15<<8) + sw);
        }
        short8 ares = *(const short8*)(rb + (l15<<8) + ((((wid<<2)+quad) ^ l15) << 4));
        floatx4 acc1[2], acc2[2];
        acc1[0] = __builtin_amdgcn_mfma_f32_16x16x32_bf16(ares, If0, (floatx4)0.f, 0,0,0);
        acc1[1] = __builtin_amdgcn_mfma_f32_16x16x32_bf16(ares, If1, (floatx4)0.f, 0,0,0);
        acc2[0] = (floatx4)0.f; acc2[1] = (floatx4)0.f;
        #pragma unroll
        for (int j = 0; j < 2; j++){
            #pragma unroll
            for (int kk = 0; kk < 4; kk++)
                acc1[j] = __builtin_amdgcn_mfma_f32_16x16x32_bf16(a1f[kk], bfr1[j][kk], acc1[j], 0,0,0);
            #pragma unroll
            for (int kk = 0; kk < 4; kk++)
                acc2[j] = __builtin_amdgcn_mfma_f32_16x16x32_bf16(a2f[kk], bfr2[j][kk], acc2[j], 0,0,0);
        }
        #pragma unroll
        for (int j = 0; j < 2; j++){
            int col = strip + j*16 + l15;
            #pragma unroll
            for (int rr = 0; rr < 4; rr++){
                int grow = row0 + quad*4 + rr;
                float v = acc1[j][rr] + invS*(acc2[j][rr] + sdv[rr]*bc2[j]) + bcol[j];
                v = fmaxf(v, 0.f);
                if constexpr (STORE){
                    A1[(size_t)grow*H + col] = f2bf(v);       // 8 ushort stores
                    outF8[(size_t)grow*H + col] = f2fp8(v);   // 8 byte stores
                } else {
                    cs[j] += v;
                }
            }
        }
        int tn = t + G;
        if (tn >= tiles) break;
        int tnn = tn + G;
        int bo2 = bo + 8192; if (bo2 >= 24576) bo2 = 0;
        int bo3 = bo2 + 8192; if (bo3 >= 24576) bo3 = 0;
        // wait for stage(tn): newer ops = 1 sdeg + (16|0) stores (+2 stage)
        if (tnn < tiles){
            STAGE_UP(bo3, tnn);
            if constexpr (STORE) asm volatile("s_waitcnt vmcnt(19)\ns_barrier" ::: "memory");
            else                 asm volatile("s_waitcnt vmcnt(3)\ns_barrier" ::: "memory");
        } else {
            if constexpr (STORE) asm volatile("s_waitcnt vmcnt(17)\ns_barrier" ::: "memory");
            else                 asm volatile("s_waitcnt vmcnt(1)\ns_barrier" ::: "memory");
        }
        t = tn; bo = bo2;
    }
    #undef STAGE_UP
    if constexpr (!STORE){
        #pragma unroll
        for (int j = 0; j < 2; j++){
            float v = cs[j];
            v += __shfl_xor(v, 16); v += __shfl_xor(v, 32);
            if (quad == 0) atomicAdd(&csum[strip + j*16 + l15], v);
        }
        __syncthreads();
        if (tid < H) atomicAdd(&colsum[((blockIdx.x & 31) << 7) + tid], csum[tid]);
    }
}

// ---------------- tiny MLP head (reduces 32 mean shadow copies) --------------
__global__ __launch_bounds__(256) void k_head(
    const float* __restrict__ meanPsh, const float* __restrict__ meanTsh,
    float invP, float invT,
    const float* __restrict__ Wpp, const float* __restrict__ bpp,
    const float* __restrict__ Wtp, const float* __restrict__ btp,
    const float* __restrict__ prefix,
    const float* __restrict__ W1, const float* __restrict__ b1,
    const float* __restrict__ W2, const float* __restrict__ b2,
    float* __restrict__ h2g)
{
    __shared__ float mp[128], mt[128];
    __shared__ float comb[384];
    __shared__ float h1s[256];
    int tid = threadIdx.x;
    if (tid < 128){
        float s = 0.f;
        for (int c = 0; c < 32; c++) s += meanPsh[(c << 7) + tid];
        mp[tid] = s;
    } else {
        int c2 = tid - 128;
        float s = 0.f;
        for (int c = 0; c < 32; c++) s += meanTsh[(c << 7) + c2];
        mt[c2] = s;
    }
    __syncthreads();
    if (tid < 128){
        float a = bpp[tid];
        for (int k = 0; k < 128; k++) a += mp[k]*invP*Wpp[k*H + tid];
        comb[tid] = a;
        comb[256 + tid] = prefix[tid];
    } else {
        int c = tid - 128;
        float a = btp[c];
        for (int k = 0; k < 128; k++) a += mt[k]*invT*Wtp[k*H + c];
        comb[128 + c] = a;
    }
    __syncthreads();
    {
        float a = b1[tid];
        for (int k = 0; k < 384; k++) a += comb[k]*W1[k*256 + tid];
        h1s[tid] = fmaxf(a, 0.f);
    }
    __syncthreads();
    if (tid < 128){
        float a = b2[tid];
        for (int k = 0; k < 256; k++) a += h1s[k]*W2[k*H + tid];
        h2g[tid] = fmaxf(a, 0.f);
    }
}

// ---------------- logits + sigmoid ----------------
__global__ __launch_bounds__(256) void k_logits(
    const float* __restrict__ h2g, const float* __restrict__ W3,
    const float* __restrict__ b3, float* __restrict__ out, int T)
{
    __shared__ float h2l[128];
    int tid = threadIdx.x;
    if (tid < 128) h2l[tid] = h2g[tid];
    __syncthreads();
    int t = blockIdx.x*256 + tid;
    if (t >= T) return;
    float a = b3[t];
    #pragma unroll 8
    for (int k = 0; k < 128; k++) a += h2l[k]*W3[(size_t)k*T + t];
    out[t] = 1.f/(1.f + expf(-a));
}

// ---------------- launch ----------------
extern "C" void kernel_launch(void* const* d_in, const int* in_sizes, int n_in,
                              void* d_out, int out_size, void* d_ws, size_t ws_size,
                              hipStream_t stream)
{
    (void)n_in; (void)out_size; (void)ws_size;
    const float* pf    = (const float*)d_in[0];
    const float* tf    = (const float*)d_in[1];
    const float* pe    = (const float*)d_in[2];
    const int*   pre   = (const int*)d_in[3];
    const int*   post  = (const int*)d_in[4];
    const float* W_pe  = (const float*)d_in[5];
    const float* b_pe  = (const float*)d_in[6];
    const float* W_te  = (const float*)d_in[7];
    const float* b_te  = (const float*)d_in[8];
    const float* W_pr  = (const float*)d_in[9];
    const float* b_pr  = (const float*)d_in[10];
    const float* p2t_W = (const float*)d_in[11];
    const float* p2t_b = (const float*)d_in[12];
    const float* t2p_W = (const float*)d_in[13];
    const float* t2p_b = (const float*)d_in[14];
    const float* pu_W  = (const float*)d_in[15];
    const float* pu_b  = (const float*)d_in[16];
    const float* tu_W  = (const float*)d_in[17];
    const float* tu_b  = (const float*)d_in[18];
    const float* pa_W  = (const float*)d_in[19];
    const float* pa_b  = (const float*)d_in[20];
    const float* ta_W  = (const float*)d_in[21];
    const float* ta_b  = (const float*)d_in[22];
    const float* W_pp  = (const float*)d_in[23];
    const float* b_pp  = (const float*)d_in[24];
    const float* W_tp  = (const float*)d_in[25];
    const float* b_tp  = (const float*)d_in[26];
    const float* W1    = (const float*)d_in[27];
    const float* b1    = (const float*)d_in[28];
    const float* W2    = (const float*)d_in[29];
    const float* b2    = (const float*)d_in[30];
    const float* W3    = (const float*)d_in[31];
    const float* b3    = (const float*)d_in[32];

    int P = in_sizes[0];
    int T = in_sizes[1] / 8;
    int E = in_sizes[3] / 2;
    int plen = in_sizes[2];
    int L = in_sizes[11] / (H*H);

    float* ws = (float*)d_ws;
    size_t fP = (size_t)P*H, fT = (size_t)T*H;
    size_t fN = (fP > fT) ? fP : fT;
    int   Nmax = (P > T) ? P : T;

    float* yA    = ws;                    // [Nmax] place-side scores
    float* yB    = yA + Nmax;             // [Nmax] trans-side scores
    float* sdegA = yB + Nmax;             // [Nmax] per-trans sum of exp
    float* sdegB = sdegA + Nmax;          // [Nmax] per-place sum of exp
    float* sc    = sdegB + Nmax;          // 16 slots (Mk at l*4+0 / l*4+2)
    float* SpSh  = sc + 16;               // [L*2*32] sharded softmax denoms
    float* meanPsh = SpSh + 192;          // [32*128] colsum shadow copies
    float* meanTsh = meanPsh + 4096;      // [32*128]
    float* prefix  = meanTsh + 4096;      // [128]
    float* h2g     = prefix + 128;        // [128]
    float* wvv  = h2g + 128;              // [L*2*128] folded score vectors
    float* c0v  = wvv + (size_t)L*256;    // [32] folded score consts (padded)
    float* bcv  = c0v + 32;               // [L*2*128] folded bias rows

    ushort_t* bh = (ushort_t*)(bcv + (size_t)L*256);
    ushort_t* place_h = bh;               // [P,128] bf16 (updated IN-PLACE)
    ushort_t* trans_h = place_h + fP;     // [T,128] bf16 (updated IN-PLACE)
    ushort_t* GbA     = trans_h + fT;     // [Nmax,128] gathered places (per trans)
    ushort_t* GbB     = GbA + fN;         // [Nmax,128] gathered transes (per place)
    ushort_t* WTb     = GbB + fN;         // L*65536 bf16 combined update weights
    uchar_t*  XP      = (uchar_t*)(WTb + (size_t)L*65536);  // [P,128] fp8 shadow
    uchar_t*  XT      = XP + fP;                             // [T,128] fp8 shadow

    int* iw = (int*)(XT + fT);
    int* cntPre  = iw;                 // [T]
    int* cntPost = cntPre + T;         // [P]
    int* rpPre   = cntPost + P;        // [T+1]
    int* rpPost  = rpPre + (T + 1);    // [P+1]
    int* csrPre  = rpPost + (P + 2);   // [E]
    int* csrPost = csrPre + E;         // [E]
    int* rankPre = csrPost + E;        // [E]
    int* rankPost= rankPre + E;        // [E]
    int* bsumA   = rankPost + E;       // [256]
    int* bsumB   = bsumA + 256;        // [256]

    const int* pre_src  = pre;          const int* pre_dst  = pre + E;
    const int* post_src = post;         const int* post_dst = post + E;

    int wtot = L*32768;
    int nbT = (T + 1023)/1024, nbP = (P + 1023)/1024;

    int tilesP = (P + 15) >> 4, tilesT = (T + 15) >> 4;
    int gridP = (tilesP + 9)/10, gridT = (tilesT + 9)/10;
    int nbTg = (T + 15) >> 4, nbPg = (P + 15) >> 4;
    int nbPemb = (P*32 + 255)/256, nbTemb = (T*32 + 255)/256;

    k_init_small<<<1, 128, 0, stream>>>(pe, plen, W_pr, b_pr, prefix,
                                        meanPsh, meanTsh, sc, SpSh);
    k_wprep2<<<(wtot + 255)/256, 256, 0, stream>>>(p2t_W, t2p_W, tu_W, pu_W, WTb, wtot);
    k_wsmall<<<L*2, 128, 0, stream>>>(p2t_W, t2p_W, tu_W, pu_W, p2t_b, t2p_b,
                                      ta_W, ta_b, pa_W, pa_b, wvv, c0v, bcv);
    k_zero_ints<<<256, 256, 0, stream>>>(iw, P + T);
    k_hist2<<<2048, 256, 0, stream>>>(pre_dst, post_dst, E,
                                      cntPre, cntPost, rankPre, rankPost);
    k_scan_part<<<nbT, 256, 0, stream>>>(cntPre, T, bsumA);
    k_scan_bsum<<<1, 256, 0, stream>>>(bsumA, nbT);
    k_scan_final<<<nbT, 256, 0, stream>>>(cntPre, T, bsumA, rpPre, E);
    k_scan_part<<<nbP, 256, 0, stream>>>(cntPost, P, bsumB);
    k_scan_bsum<<<1, 256, 0, stream>>>(bsumB, nbP);
    k_scan_final<<<nbP, 256, 0, stream>>>(cntPost, P, bsumB, rpPost, E);
    k_fill2<<<1024, 256, 0, stream>>>(pre_src, pre_dst, post_src, post_dst, E,
                                      rpPre, rankPre, csrPre,
                                      rpPost, rankPost, csrPost);

    k_embed2<<<nbPemb + nbTemb, 256, 0, stream>>>(pf, W_pe, b_pe, tf, W_te, b_te,
                                                  place_h, XP, trans_h, XT,
                                                  P, T, nbPemb);

    for (int l = 0; l < L; l++){
        const ushort_t* WTl = WTb + (size_t)l*65536;
        const float* pub  = pu_b  + (size_t)l*H;
        const float* tub  = tu_b  + (size_t)l*H;
        const float* wvA  = wvv + (size_t)(l*2 + 0)*H;
        const float* wvB  = wvv + (size_t)(l*2 + 1)*H;
        const float* bcA  = bcv + (size_t)(l*2 + 0)*H;
        const float* bcB  = bcv + (size_t)(l*2 + 1)*H;
        float* SpShl = SpSh + l*64;
        unsigned* MkA = (unsigned*)(sc + l*4 + 0);
        unsigned* MkB = (unsigned*)(sc + l*4 + 2);
        int last = (l == L-1);

        // scores (both sides, from current states) -> gather -> update
        k_gemv2<<<1024, 256, 0, stream>>>(place_h, P, trans_h, T, wvA, wvB,
                                          c0v, l*2 + 0, l*2 + 1, yA, yB, MkA, MkB);
        k_gather2<<<nbTg + nbPg, 256, 0, stream>>>(rpPre, csrPre, T,
                                                   rpPost, csrPost, P,
                                                   yA, yB, MkA, MkB, XP, XT,
                                                   GbA, GbB, sdegA, sdegB, SpShl);
        if (last)
            k_up2<false><<<gridT + gridP, 256, 0, stream>>>(
                trans_h, place_h, GbA, GbB, WTl, tub, pub, bcA, bcB,
                SpShl, sdegA, sdegB, XT, XP, T, P, gridT, gridP,
                meanTsh, meanPsh);
        else
            k_up2<true><<<gridT + gridP, 256, 0, stream>>>(
                trans_h, place_h, GbA, GbB, WTl, tub, pub, bcA, bcB,
                SpShl, sdegA, sdegB, XT, XP, T, P, gridT, gridP,
                meanTsh, meanPsh);
    }

    k_head<<<1, 256, 0, stream>>>(meanPsh, meanTsh, 1.f/(float)P, 1.f/(float)T,
                                  W_pp, b_pp, W_tp, b_tp, prefix, W1, b1, W2, b2, h2g);
    k_logits<<<(T + 255)/256, 256, 0, stream>>>(h2g, W3, b3, (float*)d_out, T);
}

// Round 10
// 637.775 us; speedup vs baseline: 1.1587x; 1.1587x over previous
//
#include <hip/hip_runtime.h>
#include <cstddef>

#define H 128

typedef unsigned short ushort_t;
typedef unsigned char uchar_t;
typedef __attribute__((ext_vector_type(8))) short short8;
typedef __attribute__((ext_vector_type(4))) float floatx4;
typedef __attribute__((ext_vector_type(2))) float floatx2;

// ---------------- helpers ----------------
__device__ __forceinline__ unsigned fkey(float f){
    unsigned u = __float_as_uint(f);
    return (u & 0x80000000u) ? ~u : (u | 0x80000000u);
}
__device__ __forceinline__ float funkey(unsigned k){
    unsigned u = (k & 0x80000000u) ? (k ^ 0x80000000u) : ~k;
    return __uint_as_float(u);
}
__device__ __forceinline__ ushort_t f2bf(float f){
    unsigned u = __float_as_uint(f);
    u += 0x7fffu + ((u >> 16) & 1u);      // round-to-nearest-even
    return (ushort_t)(u >> 16);
}
__device__ __forceinline__ float bf2f(ushort_t h){
    return __uint_as_float(((unsigned)h) << 16);
}
__device__ __forceinline__ uchar_t f2fp8(float v){
    int p = __builtin_amdgcn_cvt_pk_fp8_f32(v, v, 0, false);
    return (uchar_t)(p & 0xff);
}
// async global -> LDS, 16B per lane. LDS dest = wave-uniform base + lane*16.
__device__ __forceinline__ void gll16(const void* g, void* l){
    __builtin_amdgcn_global_load_lds(
        (const __attribute__((address_space(1))) unsigned int*)g,
        (__attribute__((address_space(3))) unsigned int*)l, 16, 0, 0);
}
// accumulate 8 fp8 (one int2) into 8 fp32 with weight
__device__ __forceinline__ void acc8f8(float* a, int2 u, float w){
    floatx2 p;
    p = __builtin_amdgcn_cvt_pk_f32_fp8(u.x, false); a[0] += w*p.x; a[1] += w*p.y;
    p = __builtin_amdgcn_cvt_pk_f32_fp8(u.x, true);  a[2] += w*p.x; a[3] += w*p.y;
    p = __builtin_amdgcn_cvt_pk_f32_fp8(u.y, false); a[4] += w*p.x; a[5] += w*p.y;
    p = __builtin_amdgcn_cvt_pk_f32_fp8(u.y, true);  a[6] += w*p.x; a[7] += w*p.y;
}

// ---------------- fused embeddings (bf16 states + fp8 shadows) ---------------
// blocks [0, nbP): place side; rest: trans side.
__global__ __launch_bounds__(256) void k_embed2(
    const float* __restrict__ pf, const float* __restrict__ Wpe,
    const float* __restrict__ bpe,
    const float* __restrict__ tf, const float* __restrict__ Wte,
    const float* __restrict__ bte,
    ushort_t* __restrict__ outP, uchar_t* __restrict__ xP,
    ushort_t* __restrict__ outT, uchar_t* __restrict__ xT,
    int P, int T, int nbP)
{
    int tid = threadIdx.x;
    if ((int)blockIdx.x < nbP){
        int idx = blockIdx.x*256 + tid;
        if (idx >= P*32) return;
        int p = idx >> 5, q = (idx & 31) << 2;
        float v = pf[p];
        float4 w = *(const float4*)(Wpe + q);
        float4 b = *(const float4*)(bpe + q);
        float v0 = v*w.x + b.x, v1 = v*w.y + b.y, v2 = v*w.z + b.z, v3 = v*w.w + b.w;
        ushort4 o;
        o.x = f2bf(v0); o.y = f2bf(v1); o.z = f2bf(v2); o.w = f2bf(v3);
        *(ushort4*)(outP + (size_t)p*H + q) = o;
        int pk = __builtin_amdgcn_cvt_pk_fp8_f32(v0, v1, 0, false);
        pk = __builtin_amdgcn_cvt_pk_fp8_f32(v2, v3, pk, true);
        *(int*)(xP + (size_t)p*H + q) = pk;
    } else {
        __shared__ float Wl[8*H];
        __shared__ float Bl[H];
        #pragma unroll
        for (int t = 0; t < 4; t++) Wl[tid + t*256] = Wte[tid + t*256];
        if (tid < H) Bl[tid] = bte[tid];
        __syncthreads();
        int idx = (blockIdx.x - nbP)*256 + tid;
        if (idx >= T*32) return;
        int t = idx >> 5, q = (idx & 31) << 2;
        float4 acc = *(float4*)(&Bl[q]);
        #pragma unroll
        for (int k = 0; k < 8; k++){
            float s = tf[(size_t)t*8 + k];
            float4 w = *(float4*)(&Wl[k*H + q]);
            acc.x += s*w.x; acc.y += s*w.y; acc.z += s*w.z; acc.w += s*w.w;
        }
        ushort4 o;
        o.x = f2bf(acc.x); o.y = f2bf(acc.y); o.z = f2bf(acc.z); o.w = f2bf(acc.w);
        *(ushort4*)(outT + (size_t)t*H + q) = o;
        int pk = __builtin_amdgcn_cvt_pk_fp8_f32(acc.x, acc.y, 0, false);
        pk = __builtin_amdgcn_cvt_pk_fp8_f32(acc.z, acc.w, pk, true);
        *(int*)(xT + (size_t)t*H + q) = pk;
    }
}

// prefix embedding + zero mean shadow copies + softmax slots + Sp shards
__global__ void k_init_small(const float* __restrict__ pe, int plen,
                             const float* __restrict__ Wpr, const float* __restrict__ bpr,
                             float* __restrict__ prefix, float* __restrict__ meanPsh,
                             float* __restrict__ meanTsh, float* __restrict__ slots,
                             float* __restrict__ SpSh)
{
    int c = threadIdx.x;  // 128 threads
    float a = bpr[c];
    for (int k = 0; k < plen; k++) a += pe[k]*Wpr[k*H + c];
    prefix[c] = a;
    for (int i = c; i < 4096; i += 128){ meanPsh[i] = 0.f; meanTsh[i] = 0.f; }
    for (int i = c; i < 192; i += 128) SpSh[i] = 0.f;
    if (c < 16) slots[c] = 0.f;   // fkey-space 0 == -inf
}

// ---------------- combined weight prep: A1-half + folded Wc ------------------
__global__ __launch_bounds__(256) void k_wprep2(
    const float* __restrict__ p2t_W, const float* __restrict__ t2p_W,
    const float* __restrict__ tu_W,  const float* __restrict__ pu_W,
    ushort_t* __restrict__ WT, int total)   // total = L*32768
{
    int e = blockIdx.x*256 + threadIdx.x;
    if (e >= total) return;
    int l = e / 32768, oo = e - l*32768;
    int side = oo >> 14, o2 = oo & 16383;
    int n = o2 >> 7, k = o2 & 127;
    const float* A  = side ? (t2p_W + (size_t)l*16384) : (p2t_W + (size_t)l*16384);
    const float* Bm = side ? (pu_W  + (size_t)l*32768) : (tu_W  + (size_t)l*32768);
    ushort_t* dst = WT + (size_t)l*65536 + (size_t)side*32768 + n*256;
    dst[k] = f2bf(Bm[(size_t)k*H + n]);                  // Wtop half
    const float* Ar = A + (size_t)k*H;
    const float* Bc = Bm + (size_t)128*H + n;
    float s = 0.f;
    #pragma unroll 4
    for (int j = 0; j < 128; j++) s += Ar[j] * Bc[(size_t)j*H];
    dst[128 + k] = f2bf(s);                              // folded Wc half
}

// ---------------- folded small vectors: wv, bc, c0 ---------------------------
__global__ __launch_bounds__(128) void k_wsmall(
    const float* __restrict__ p2t_W, const float* __restrict__ t2p_W,
    const float* __restrict__ tu_W,  const float* __restrict__ pu_W,
    const float* __restrict__ p2t_b, const float* __restrict__ t2p_b,
    const float* __restrict__ ta_W,  const float* __restrict__ ta_b,
    const float* __restrict__ pa_W,  const float* __restrict__ pa_b,
    float* __restrict__ wv, float* __restrict__ c0v, float* __restrict__ bcv)
{
    int b = blockIdx.x, l = b >> 1, side = b & 1;
    const float* A  = side ? (t2p_W + (size_t)l*16384) : (p2t_W + (size_t)l*16384);
    const float* Bm = side ? (pu_W  + (size_t)l*32768) : (tu_W  + (size_t)l*32768);
    const float* ab = side ? (t2p_b + (size_t)l*H) : (p2t_b + (size_t)l*H);
    const float* av = side ? (pa_W  + (size_t)l*H) : (ta_W  + (size_t)l*H);
    float asc       = side ? pa_b[l] : ta_b[l];
    int tid = threadIdx.x;
    int o = (l*2 + side)*H;
    float s = 0.f;
    for (int n = 0; n < 128; n++) s += A[(size_t)tid*H + n] * av[n];
    wv[o + tid] = s;
    float s2 = 0.f;
    for (int j = 0; j < 128; j++) s2 += ab[j] * Bm[(size_t)(128+j)*H + tid];
    bcv[o + tid] = s2;
    if (tid == 0){
        float c = 0.f;
        for (int n = 0; n < 128; n++) c += ab[n]*av[n];
        c0v[l*2 + side] = c + asc;
    }
}

// ---------------- CSR build ----------------
__global__ __launch_bounds__(256) void k_zero_ints(int* __restrict__ p, int n)
{
    int i = blockIdx.x*256 + threadIdx.x;
    int stride = gridDim.x*256;
    for (; i < n; i += stride) p[i] = 0;
}

__global__ __launch_bounds__(256) void k_hist2(
    const int* __restrict__ preD, const int* __restrict__ postD, int E,
    int* __restrict__ cntPre, int* __restrict__ cntPost,
    int* __restrict__ rankPre, int* __restrict__ rankPost)
{
    int i = blockIdx.x*256 + threadIdx.x;
    int stride = gridDim.x*256;
    for (; i < E; i += stride){
        rankPre[i] = atomicAdd(&cntPre[preD[i]], 1);
        rankPost[i] = atomicAdd(&cntPost[postD[i]], 1);
    }
}

__global__ __launch_bounds__(256) void k_scan_part(
    const int* __restrict__ cnt, int N, int* __restrict__ bsum)
{
    __shared__ int wsum[4];
    int tid = threadIdx.x, lane = tid & 63, wid = tid >> 6;
    int base = blockIdx.x*1024 + tid*4;
    int4 v = make_int4(0,0,0,0);
    if (base + 3 < N) v = *(const int4*)(cnt + base);
    else {
        if (base+0 < N) v.x = cnt[base+0];
        if (base+1 < N) v.y = cnt[base+1];
        if (base+2 < N) v.z = cnt[base+2];
    }
    int s = v.x + v.y + v.z + v.w;
    #pragma unroll
    for (int o = 1; o < 64; o <<= 1) s += __shfl_xor(s, o);
    if (lane == 0) wsum[wid] = s;
    __syncthreads();
    if (tid == 0) bsum[blockIdx.x] = wsum[0] + wsum[1] + wsum[2] + wsum[3];
}

__global__ __launch_bounds__(256) void k_scan_bsum(int* __restrict__ bsum, int nb)
{
    __shared__ int wsum[4];
    int tid = threadIdx.x, lane = tid & 63, wid = tid >> 6;
    int x = (tid < nb) ? bsum[tid] : 0;
    int inc = x;
    #pragma unroll
    for (int o = 1; o < 64; o <<= 1){
        int u = __shfl_up(inc, o);
        if (lane >= o) inc += u;
    }
    if (lane == 63) wsum[wid] = inc;
    __syncthreads();
    int woff = 0;
    if (wid > 0) woff += wsum[0];
    if (wid > 1) woff += wsum[1];
    if (wid > 2) woff += wsum[2];
    if (tid < nb) bsum[tid] = woff + inc - x;
}

__global__ __launch_bounds__(256) void k_scan_final(
    const int* __restrict__ cnt, int N, const int* __restrict__ bsum,
    int* __restrict__ rp, int E)
{
    __shared__ int wsum[4];
    int tid = threadIdx.x, lane = tid & 63, wid = tid >> 6;
    int base = blockIdx.x*1024 + tid*4;
    int4 v = make_int4(0,0,0,0);
    if (base + 3 < N) v = *(const int4*)(cnt + base);
    else {
        if (base+0 < N) v.x = cnt[base+0];
        if (base+1 < N) v.y = cnt[base+1];
        if (base+2 < N) v.z = cnt[base+2];
    }
    int t0 = v.x, t1 = t0 + v.y, t2 = t1 + v.z, t3 = t2 + v.w;
    int inc = t3;
    #pragma unroll
    for (int o = 1; o < 64; o <<= 1){
        int u = __shfl_up(inc, o);
        if (lane >= o) inc += u;
    }
    if (lane == 63) wsum[wid] = inc;
    __syncthreads();
    int woff = 0;
    if (wid > 0) woff += wsum[0];
    if (wid > 1) woff += wsum[1];
    if (wid > 2) woff += wsum[2];
    int off = bsum[blockIdx.x] + woff + inc - t3;
    if (base+0 < N) rp[base+0] = off;
    if (base+1 < N) rp[base+1] = off + t0;
    if (base+2 < N) rp[base+2] = off + t1;
    if (base+3 < N) rp[base+3] = off + t2;
    if (blockIdx.x == 0 && tid == 0) rp[N] = E;
}

__global__ __launch_bounds__(256) void k_fill2(
    const int* __restrict__ preS, const int* __restrict__ preD,
    const int* __restrict__ postS, const int* __restrict__ postD, int E,
    const int* __restrict__ rpPre, const int* __restrict__ rankPre, int* __restrict__ csrPre,
    const int* __restrict__ rpPost, const int* __restrict__ rankPost, int* __restrict__ csrPost)
{
    int i = blockIdx.x*256 + threadIdx.x;
    int stride = gridDim.x*256;
    for (; i < E; i += stride){
        csrPre[rpPre[preD[i]] + rankPre[i]] = preS[i];
        csrPost[rpPost[postD[i]] + rankPost[i]] = postS[i];
    }
}

// ---------------- dual-side score GEMV: y[r] = h[r].wv + c0, fused max -------
__global__ __launch_bounds__(256) void k_gemv2(
    const ushort_t* __restrict__ Ap, int P,
    const ushort_t* __restrict__ At, int T,
    const float* __restrict__ wvA, const float* __restrict__ wvB,
    const float* __restrict__ c0v, int c0iA, int c0iB,
    float* __restrict__ yA, float* __restrict__ yB,
    unsigned* __restrict__ MkA, unsigned* __restrict__ MkB)
{
    __shared__ float wm[4];
    int half = gridDim.x >> 1;
    int side = (blockIdx.x >= half);
    const ushort_t* A = side ? At : Ap;
    int M = side ? T : P;
    const float* wv = side ? wvB : wvA;
    float c0 = c0v[side ? c0iB : c0iA];
    float* y = side ? yB : yA;
    unsigned* Mk = side ? MkB : MkA;
    int b = side ? (blockIdx.x - half) : blockIdx.x;

    int tid = threadIdx.x, lane = tid & 63, wid = tid >> 6;
    int g = tid >> 4, gl = tid & 15;
    float w8[8];
    #pragma unroll
    for (int i = 0; i < 8; i++) w8[i] = wv[gl*8 + i];
    int stride = half*16;
    float lmax = -3.402823466e38f;
    for (int r = b*16 + g; r < M; r += stride){
        short8 u = *(const short8*)(A + (size_t)r*H + gl*8);
        float s = 0.f;
        #pragma unroll
        for (int i = 0; i < 8; i++) s += bf2f((ushort_t)u[i]) * w8[i];
        s += __shfl_xor(s, 1); s += __shfl_xor(s, 2);
        s += __shfl_xor(s, 4); s += __shfl_xor(s, 8);
        s += c0;
        if (gl == 0) y[r] = s;
        lmax = fmaxf(lmax, s);
    }
    #pragma unroll
    for (int o = 1; o < 64; o <<= 1) lmax = fmaxf(lmax, __shfl_xor(lmax, o));
    if (lane == 0) wm[wid] = lmax;
    __syncthreads();
    if (tid == 0){
        float m = fmaxf(fmaxf(wm[0], wm[1]), fmaxf(wm[2], wm[3]));
        atomicMax(Mk, fkey(m));
    }
}

// ---------------- edge weights in CSR order + sharded denominators -----------
// ew[j] = exp(y[csr[j]] - M), sequential/prefetchable (R7-validated: the
// inline-expf gather variant cost +43 µs/dispatch from y-line overfetch).
// Block sums go to 32-way SpSh shards (R6 atomic lesson).
__global__ __launch_bounds__(256) void k_ew2(
    const int* __restrict__ csrPre, const int* __restrict__ csrPost, int E,
    const float* __restrict__ yA, const float* __restrict__ yB,
    const unsigned* __restrict__ MkA, const unsigned* __restrict__ MkB,
    float* __restrict__ ewA, float* __restrict__ ewB,
    float* __restrict__ SpShl)
{
    __shared__ float red[4];
    int half = gridDim.x >> 1;
    int side = (blockIdx.x >= half);
    const int* csr = side ? csrPost : csrPre;
    const float* y = side ? yB : yA;
    float Mv = funkey((side ? MkB : MkA)[0]);
    float* ew = side ? ewB : ewA;
    int b = side ? (blockIdx.x - half) : blockIdx.x;

    int tid = threadIdx.x, lane = tid & 63, wid = tid >> 6;
    int gid = b*256 + tid, stride = half*256;
    float ls = 0.f;
    for (int j = gid; j < E; j += stride){
        float w = expf(y[csr[j]] - Mv);
        ew[j] = w;
        ls += w;
    }
    #pragma unroll
    for (int o = 1; o < 64; o <<= 1) ls += __shfl_xor(ls, o);
    if (lane == 0) red[wid] = ls;
    __syncthreads();
    if (tid == 0)
        atomicAdd(&SpShl[side*32 + (blockIdx.x & 31)],
                  red[0] + red[1] + red[2] + red[3]);
}

// ---------------- dual-side CSR gather of fp8 rows + sdeg --------------------
// G[r] = sum_e ew[j] * X[csr[j]]  (UNNORMALIZED);  sdeg[r] = sum ew.
__global__ __launch_bounds__(256) void k_gather2(
    const int* __restrict__ rpPre, const int* __restrict__ csrPre, int T,
    const int* __restrict__ rpPost, const int* __restrict__ csrPost, int P,
    const float* __restrict__ ewA, const float* __restrict__ ewB,
    const uchar_t* __restrict__ XP, const uchar_t* __restrict__ XT,
    ushort_t* __restrict__ GbA, ushort_t* __restrict__ GbB,
    float* __restrict__ sdegA, float* __restrict__ sdegB)
{
    int nbT = (T + 15) >> 4;
    int side = (blockIdx.x >= nbT);
    const int* rp   = side ? rpPost : rpPre;
    const int* csr  = side ? csrPost : csrPre;
    const float* ew = side ? ewB : ewA;
    const uchar_t* X = side ? XT : XP;
    ushort_t* G     = side ? GbB : GbA;
    float* sdeg     = side ? sdegB : sdegA;
    int Nrow        = side ? P : T;
    int b = side ? (blockIdx.x - nbT) : blockIdx.x;

    int tid = threadIdx.x;
    int g = tid >> 4, gl = tid & 15;          // 16 groups x 16 lanes
    int r = b*16 + g;
    if (r >= Nrow) return;
    int j0 = rp[r], j1 = rp[r+1];
    const int2* X8 = (const int2*)X;          // fp8 row = 16 int2 (128 fp8)
    float a[8] = {0.f,0.f,0.f,0.f,0.f,0.f,0.f,0.f};
    float se = 0.f;
    int j = j0;
    for (; j + 1 < j1; j += 2){
        int s0 = csr[j], s1 = csr[j+1];
        float e0 = ew[j], e1 = ew[j+1];
        int2 u0 = X8[(size_t)s0*16 + gl];
        int2 u1 = X8[(size_t)s1*16 + gl];
        se += e0 + e1;
        acc8f8(a, u0, e0);
        acc8f8(a, u1, e1);
    }
    if (j < j1){
        int s0 = csr[j];
        float e0 = ew[j];
        int2 u0 = X8[(size_t)s0*16 + gl];
        se += e0;
        acc8f8(a, u0, e0);
    }
    int4 o;
    o.x = (int)((((unsigned)f2bf(a[1])) << 16) | (unsigned)f2bf(a[0]));
    o.y = (int)((((unsigned)f2bf(a[3])) << 16) | (unsigned)f2bf(a[2]));
    o.z = (int)((((unsigned)f2bf(a[5])) << 16) | (unsigned)f2bf(a[4]));
    o.w = (int)((((unsigned)f2bf(a[7])) << 16) | (unsigned)f2bf(a[6]));
    ((int4*)G)[(size_t)r*16 + gl] = o;
    if (gl == 0) sdeg[r] = se;
}

// ---------------- dual-side update GEMM --------------------------------------
// out = relu(A1 + A1@Wtop + invS*(G@Wc + sdeg*bc) + b)   [IN-PLACE: out == A1]
// 3-buffer LDS ring (2-deep prefetch, counted vmcnt, raw s_barrier), XOR-
// swizzled via pre-swizzled global source. Residual A1 via identity-MFMA.
// invS = 1/sum(32 Sp shards). STORE vmcnt 19/17 (R7-validated). STORE=false:
// colsum into 32 shadow copies; vmcnt 3/1.
template<bool STORE>
__global__ __launch_bounds__(256, 4) void k_up2(
    ushort_t* trans_h, ushort_t* place_h,
    const ushort_t* __restrict__ GbA, const ushort_t* __restrict__ GbB,
    const ushort_t* __restrict__ WTl,
    const float* __restrict__ tub, const float* __restrict__ pub,
    const float* __restrict__ bcA, const float* __restrict__ bcB,
    const float* __restrict__ SpShl,        // [64]: side0 0..31, side1 32..63
    const float* __restrict__ sdegA, const float* __restrict__ sdegB,
    uchar_t* __restrict__ XT, uchar_t* __restrict__ XP,
    int T, int P, int gridT, int gridP,
    float* __restrict__ meanTsh, float* __restrict__ meanPsh)
{
    __shared__ __align__(16) char As[3*8192];   // 3 x (A1 4KB | A2 4KB)
    __shared__ float csum[H];
    int side = (blockIdx.x >= gridT);
    ushort_t* A1        = side ? place_h : trans_h;
    const ushort_t* A2  = side ? GbB : GbA;
    const ushort_t* WT  = WTl + (side ? 32768 : 0);
    const float* bias   = side ? pub : tub;
    const float* bcp    = side ? bcB : bcA;
    const float* sdeg   = side ? sdegB : sdegA;
    uchar_t* outF8      = side ? XP : XT;
    int M               = side ? P : T;
    int G               = side ? gridP : gridT;
    int t0              = side ? (blockIdx.x - gridT) : blockIdx.x;
    float* colsum       = side ? meanPsh : meanTsh;
    float Sv = 0.f;
    {
        const float* sp = SpShl + (side ? 32 : 0);
        #pragma unroll
        for (int i = 0; i < 32; i++) Sv += sp[i];
    }
    float invS = 1.f / Sv;

    int tid = threadIdx.x;
    int lane = tid & 63, wid = tid >> 6;
    int quad = lane >> 4, l15 = lane & 15;
    int strip = wid*32;
    short8 bfr1[2][4], bfr2[2][4];
    float bcol[2], bc2[2];
    #pragma unroll
    for (int j = 0; j < 2; j++){
        int col = strip + j*16 + l15;
        #pragma unroll
        for (int kk = 0; kk < 4; kk++){
            bfr1[j][kk] = *(const short8*)(WT + (size_t)col*256 + kk*32 + quad*8);
            bfr2[j][kk] = *(const short8*)(WT + (size_t)col*256 + 128 + kk*32 + quad*8);
        }
        bcol[j] = bias[col];
        bc2[j]  = bcp[col];
    }
    // identity B-fragments: transpose the wave's A1 fragment window into C-layout
    short8 If0, If1;
    #pragma unroll
    for (int e = 0; e < 8; e++){
        int kloc = quad*8 + e;
        If0[e] = (kloc == l15)      ? (short)0x3F80 : (short)0;
        If1[e] = (kloc == l15 + 16) ? (short)0x3F80 : (short)0;
    }
    if constexpr (!STORE){ if (tid < H) csum[tid] = 0.f; }
    float cs[2] = {0.f, 0.f};

    int tiles = (M + 15) >> 4;
    if (t0 >= tiles) return;
    int srow = tid >> 4;
    int su = (tid & 15) ^ srow;
    const ushort_t* g1b = A1 + (size_t)srow*H + su*8;
    const ushort_t* g2b = A2 + (size_t)srow*H + su*8;
    char* AsB = As;

    #define STAGE_UP(bo, t) do { \
        gll16(g1b + (size_t)(t)*(16*H), AsB + (bo) + (wid<<10)); \
        gll16(g2b + (size_t)(t)*(16*H), AsB + (bo) + 4096 + (wid<<10)); \
    } while(0)

    STAGE_UP(0, t0);
    int t1p = t0 + G;
    if (t1p < tiles){
        STAGE_UP(8192, t1p);
        asm volatile("s_waitcnt vmcnt(2)\ns_barrier" ::: "memory");
    } else {
        asm volatile("s_waitcnt vmcnt(0)\ns_barrier" ::: "memory");
    }

    int t = t0, bo = 0;
    for (;;){
        const char* rb = AsB + bo;
        int row0 = t << 4;
        float4 sd4 = *(const float4*)(sdeg + row0 + quad*4);
        float sdv[4] = {sd4.x, sd4.y, sd4.z, sd4.w};
        short8 a1f[4], a2f[4];
        #pragma unroll
        for (int kk = 0; kk < 4; kk++){
            int sw = ((((kk<<2)+quad) ^ l15) << 4);
            a1f[kk] = *(const short8*)(rb + (l15<<8) + sw);
            a2f[kk] = *(const short8*)(rb + 4096 + (l15<<8) + sw);
        }
        short8 ares = *(const short8*)(rb + (l15<<8) + ((((wid<<2)+quad) ^ l15) << 4));
        floatx4 acc1[2], acc2[2];
        acc1[0] = __builtin_amdgcn_mfma_f32_16x16x32_bf16(ares, If0, (floatx4)0.f, 0,0,0);
        acc1[1] = __builtin_amdgcn_mfma_f32_16x16x32_bf16(ares, If1, (floatx4)0.f, 0,0,0);
        acc2[0] = (floatx4)0.f; acc2[1] = (floatx4)0.f;
        #pragma unroll
        for (int j = 0; j < 2; j++){
            #pragma unroll
            for (int kk = 0; kk < 4; kk++)
                acc1[j] = __builtin_amdgcn_mfma_f32_16x16x32_bf16(a1f[kk], bfr1[j][kk], acc1[j], 0,0,0);
            #pragma unroll
            for (int kk = 0; kk < 4; kk++)
                acc2[j] = __builtin_amdgcn_mfma_f32_16x16x32_bf16(a2f[kk], bfr2[j][kk], acc2[j], 0,0,0);
        }
        #pragma unroll
        for (int j = 0; j < 2; j++){
            int col = strip + j*16 + l15;
            #pragma unroll
            for (int rr = 0; rr < 4; rr++){
                int grow = row0 + quad*4 + rr;
                float v = acc1[j][rr] + invS*(acc2[j][rr] + sdv[rr]*bc2[j]) + bcol[j];
                v = fmaxf(v, 0.f);
                if constexpr (STORE){
                    A1[(size_t)grow*H + col] = f2bf(v);       // 8 ushort stores
                    outF8[(size_t)grow*H + col] = f2fp8(v);   // 8 byte stores
                } else {
                    cs[j] += v;
                }
            }
        }
        int tn = t + G;
        if (tn >= tiles) break;
        int tnn = tn + G;
        int bo2 = bo + 8192; if (bo2 >= 24576) bo2 = 0;
        int bo3 = bo2 + 8192; if (bo3 >= 24576) bo3 = 0;
        // wait for stage(tn): newer ops = 1 sdeg + (16|0) stores (+2 stage)
        if (tnn < tiles){
            STAGE_UP(bo3, tnn);
            if constexpr (STORE) asm volatile("s_waitcnt vmcnt(19)\ns_barrier" ::: "memory");
            else                 asm volatile("s_waitcnt vmcnt(3)\ns_barrier" ::: "memory");
        } else {
            if constexpr (STORE) asm volatile("s_waitcnt vmcnt(17)\ns_barrier" ::: "memory");
            else                 asm volatile("s_waitcnt vmcnt(1)\ns_barrier" ::: "memory");
        }
        t = tn; bo = bo2;
    }
    #undef STAGE_UP
    if constexpr (!STORE){
        #pragma unroll
        for (int j = 0; j < 2; j++){
            float v = cs[j];
            v += __shfl_xor(v, 16); v += __shfl_xor(v, 32);
            if (quad == 0) atomicAdd(&csum[strip + j*16 + l15], v);
        }
        __syncthreads();
        if (tid < H) atomicAdd(&colsum[((blockIdx.x & 31) << 7) + tid], csum[tid]);
    }
}

// ---------------- tiny MLP head (reduces 32 mean shadow copies) --------------
__global__ __launch_bounds__(256) void k_head(
    const float* __restrict__ meanPsh, const float* __restrict__ meanTsh,
    float invP, float invT,
    const float* __restrict__ Wpp, const float* __restrict__ bpp,
    const float* __restrict__ Wtp, const float* __restrict__ btp,
    const float* __restrict__ prefix,
    const float* __restrict__ W1, const float* __restrict__ b1,
    const float* __restrict__ W2, const float* __restrict__ b2,
    float* __restrict__ h2g)
{
    __shared__ float mp[128], mt[128];
    __shared__ float comb[384];
    __shared__ float h1s[256];
    int tid = threadIdx.x;
    if (tid < 128){
        float s = 0.f;
        for (int c = 0; c < 32; c++) s += meanPsh[(c << 7) + tid];
        mp[tid] = s;
    } else {
        int c2 = tid - 128;
        float s = 0.f;
        for (int c = 0; c < 32; c++) s += meanTsh[(c << 7) + c2];
        mt[c2] = s;
    }
    __syncthreads();
    if (tid < 128){
        float a = bpp[tid];
        for (int k = 0; k < 128; k++) a += mp[k]*invP*Wpp[k*H + tid];
        comb[tid] = a;
        comb[256 + tid] = prefix[tid];
    } else {
        int c = tid - 128;
        float a = btp[c];
        for (int k = 0; k < 128; k++) a += mt[k]*invT*Wtp[k*H + c];
        comb[128 + c] = a;
    }
    __syncthreads();
    {
        float a = b1[tid];
        for (int k = 0; k < 384; k++) a += comb[k]*W1[k*256 + tid];
        h1s[tid] = fmaxf(a, 0.f);
    }
    __syncthreads();
    if (tid < 128){
        float a = b2[tid];
        for (int k = 0; k < 256; k++) a += h1s[k]*W2[k*H + tid];
        h2g[tid] = fmaxf(a, 0.f);
    }
}

// ---------------- logits + sigmoid ----------------
__global__ __launch_bounds__(256) void k_logits(
    const float* __restrict__ h2g, const float* __restrict__ W3,
    const float* __restrict__ b3, float* __restrict__ out, int T)
{
    __shared__ float h2l[128];
    int tid = threadIdx.x;
    if (tid < 128) h2l[tid] = h2g[tid];
    __syncthreads();
    int t = blockIdx.x*256 + tid;
    if (t >= T) return;
    float a = b3[t];
    #pragma unroll 8
    for (int k = 0; k < 128; k++) a += h2l[k]*W3[(size_t)k*T + t];
    out[t] = 1.f/(1.f + expf(-a));
}

// ---------------- launch ----------------
extern "C" void kernel_launch(void* const* d_in, const int* in_sizes, int n_in,
                              void* d_out, int out_size, void* d_ws, size_t ws_size,
                              hipStream_t stream)
{
    (void)n_in; (void)out_size; (void)ws_size;
    const float* pf    = (const float*)d_in[0];
    const float* tf    = (const float*)d_in[1];
    const float* pe    = (const float*)d_in[2];
    const int*   pre   = (const int*)d_in[3];
    const int*   post  = (const int*)d_in[4];
    const float* W_pe  = (const float*)d_in[5];
    const float* b_pe  = (const float*)d_in[6];
    const float* W_te  = (const float*)d_in[7];
    const float* b_te  = (const float*)d_in[8];
    const float* W_pr  = (const float*)d_in[9];
    const float* b_pr  = (const float*)d_in[10];
    const float* p2t_W = (const float*)d_in[11];
    const float* p2t_b = (const float*)d_in[12];
    const float* t2p_W = (const float*)d_in[13];
    const float* t2p_b = (const float*)d_in[14];
    const float* pu_W  = (const float*)d_in[15];
    const float* pu_b  = (const float*)d_in[16];
    const float* tu_W  = (const float*)d_in[17];
    const float* tu_b  = (const float*)d_in[18];
    const float* pa_W  = (const float*)d_in[19];
    const float* pa_b  = (const float*)d_in[20];
    const float* ta_W  = (const float*)d_in[21];
    const float* ta_b  = (const float*)d_in[22];
    const float* W_pp  = (const float*)d_in[23];
    const float* b_pp  = (const float*)d_in[24];
    const float* W_tp  = (const float*)d_in[25];
    const float* b_tp  = (const float*)d_in[26];
    const float* W1    = (const float*)d_in[27];
    const float* b1    = (const float*)d_in[28];
    const float* W2    = (const float*)d_in[29];
    const float* b2    = (const float*)d_in[30];
    const float* W3    = (const float*)d_in[31];
    const float* b3    = (const float*)d_in[32];

    int P = in_sizes[0];
    int T = in_sizes[1] / 8;
    int E = in_sizes[3] / 2;
    int plen = in_sizes[2];
    int L = in_sizes[11] / (H*H);

    float* ws = (float*)d_ws;
    size_t fP = (size_t)P*H, fT = (size_t)T*H;
    size_t fN = (fP > fT) ? fP : fT;
    int   Nmax = (P > T) ? P : T;

    float* yA    = ws;                    // [Nmax] place-side scores
    float* yB    = yA + Nmax;             // [Nmax] trans-side scores
    float* sdegA = yB + Nmax;             // [Nmax] per-trans sum of exp
    float* sdegB = sdegA + Nmax;          // [Nmax] per-place sum of exp
    float* sc    = sdegB + Nmax;          // 16 slots (Mk at l*4+0 / l*4+2)
    float* SpSh  = sc + 16;               // [L*2*32] sharded softmax denoms
    float* meanPsh = SpSh + 192;          // [32*128] colsum shadow copies
    float* meanTsh = meanPsh + 4096;      // [32*128]
    float* prefix  = meanTsh + 4096;      // [128]
    float* h2g     = prefix + 128;        // [128]
    float* wvv  = h2g + 128;              // [L*2*128] folded score vectors
    float* c0v  = wvv + (size_t)L*256;    // [32] folded score consts (padded)
    float* bcv  = c0v + 32;               // [L*2*128] folded bias rows

    ushort_t* bh = (ushort_t*)(bcv + (size_t)L*256);
    ushort_t* place_h = bh;               // [P,128] bf16 (updated IN-PLACE)
    ushort_t* trans_h = place_h + fP;     // [T,128] bf16 (updated IN-PLACE)
    ushort_t* GbA     = trans_h + fT;     // [Nmax,128] gathered places (per trans)
    ushort_t* GbB     = GbA + fN;         // [Nmax,128] gathered transes (per place)
    ushort_t* WTb     = GbB + fN;         // L*65536 bf16 combined update weights
    uchar_t*  XP      = (uchar_t*)(WTb + (size_t)L*65536);  // [P,128] fp8 shadow
    uchar_t*  XT      = XP + fP;                             // [T,128] fp8 shadow

    int* iw = (int*)(XT + fT);
    int* cntPre  = iw;                 // [T]
    int* cntPost = cntPre + T;         // [P]
    int* rpPre   = cntPost + P;        // [T+1]
    int* rpPost  = rpPre + (T + 1);    // [P+1]
    int* csrPre  = rpPost + (P + 2);   // [E]
    int* csrPost = csrPre + E;         // [E]
    int* rankPre = csrPost + E;        // [E]
    int* rankPost= rankPre + E;        // [E]
    int* bsumA   = rankPost + E;       // [256]
    int* bsumB   = bsumA + 256;        // [256]

    // edge-weight buffers ALIAS the rank arrays (dead after k_fill2) —
    // R6/R7-validated aliasing, zero footprint growth.
    float* ewA = (float*)rankPre;      // [E] edge weights, csrPre order
    float* ewB = (float*)rankPost;     // [E] edge weights, csrPost order

    const int* pre_src  = pre;          const int* pre_dst  = pre + E;
    const int* post_src = post;         const int* post_dst = post + E;

    int wtot = L*32768;
    int nbT = (T + 1023)/1024, nbP = (P + 1023)/1024;

    int tilesP = (P + 15) >> 4, tilesT = (T + 15) >> 4;
    int gridP = (tilesP + 9)/10, gridT = (tilesT + 9)/10;
    int nbTg = (T + 15) >> 4, nbPg = (P + 15) >> 4;
    int nbPemb = (P*32 + 255)/256, nbTemb = (T*32 + 255)/256;

    k_init_small<<<1, 128, 0, stream>>>(pe, plen, W_pr, b_pr, prefix,
                                        meanPsh, meanTsh, sc, SpSh);
    k_wprep2<<<(wtot + 255)/256, 256, 0, stream>>>(p2t_W, t2p_W, tu_W, pu_W, WTb, wtot);
    k_wsmall<<<L*2, 128, 0, stream>>>(p2t_W, t2p_W, tu_W, pu_W, p2t_b, t2p_b,
                                      ta_W, ta_b, pa_W, pa_b, wvv, c0v, bcv);
    k_zero_ints<<<256, 256, 0, stream>>>(iw, P + T);
    k_hist2<<<2048, 256, 0, stream>>>(pre_dst, post_dst, E,
                                      cntPre, cntPost, rankPre, rankPost);
    k_scan_part<<<nbT, 256, 0, stream>>>(cntPre, T, bsumA);
    k_scan_bsum<<<1, 256, 0, stream>>>(bsumA, nbT);
    k_scan_final<<<nbT, 256, 0, stream>>>(cntPre, T, bsumA, rpPre, E);
    k_scan_part<<<nbP, 256, 0, stream>>>(cntPost, P, bsumB);
    k_scan_bsum<<<1, 256, 0, stream>>>(bsumB, nbP);
    k_scan_final<<<nbP, 256, 0, stream>>>(cntPost, P, bsumB, rpPost, E);
    k_fill2<<<1024, 256, 0, stream>>>(pre_src, pre_dst, post_src, post_dst, E,
                                      rpPre, rankPre, csrPre,
                                      rpPost, rankPost, csrPost);

    k_embed2<<<nbPemb + nbTemb, 256, 0, stream>>>(pf, W_pe, b_pe, tf, W_te, b_te,
                                                  place_h, XP, trans_h, XT,
                                                  P, T, nbPemb);

    for (int l = 0; l < L; l++){
        const ushort_t* WTl = WTb + (size_t)l*65536;
        const float* pub  = pu_b  + (size_t)l*H;
        const float* tub  = tu_b  + (size_t)l*H;
        const float* wvA  = wvv + (size_t)(l*2 + 0)*H;
        const float* wvB  = wvv + (size_t)(l*2 + 1)*H;
        const float* bcA  = bcv + (size_t)(l*2 + 0)*H;
        const float* bcB  = bcv + (size_t)(l*2 + 1)*H;
        float* SpShl = SpSh + l*64;
        unsigned* MkA = (unsigned*)(sc + l*4 + 0);
        unsigned* MkB = (unsigned*)(sc + l*4 + 2);
        int last = (l == L-1);

        // scores -> edge weights (sequential, + sharded denoms) -> gather -> update
        k_gemv2<<<1024, 256, 0, stream>>>(place_h, P, trans_h, T, wvA, wvB,
                                          c0v, l*2 + 0, l*2 + 1, yA, yB, MkA, MkB);
        k_ew2<<<1024, 256, 0, stream>>>(csrPre, csrPost, E, yA, yB, MkA, MkB,
                                        ewA, ewB, SpShl);
        k_gather2<<<nbTg + nbPg, 256, 0, stream>>>(rpPre, csrPre, T,
                                                   rpPost, csrPost, P,
                                                   ewA, ewB, XP, XT,
                                                   GbA, GbB, sdegA, sdegB);
        if (last)
            k_up2<false><<<gridT + gridP, 256, 0, stream>>>(
                trans_h, place_h, GbA, GbB, WTl, tub, pub, bcA, bcB,
                SpShl, sdegA, sdegB, XT, XP, T, P, gridT, gridP,
                meanTsh, meanPsh);
        else
            k_up2<true><<<gridT + gridP, 256, 0, stream>>>(
                trans_h, place_h, GbA, GbB, WTl, tub, pub, bcA, bcB,
                SpShl, sdegA, sdegB, XT, XP, T, P, gridT, gridP,
                meanTsh, meanPsh);
    }

    k_head<<<1, 256, 0, stream>>>(meanPsh, meanTsh, 1.f/(float)P, 1.f/(float)T,
                                  W_pp, b_pp, W_tp, b_tp, prefix, W1, b1, W2, b2, h2g);
    k_logits<<<(T + 255)/256, 256, 0, stream>>>(h2g, W3, b3, (float*)d_out, T);
}

// Round 11
// 632.771 us; speedup vs baseline: 1.1679x; 1.0079x over previous
//
#include <hip/hip_runtime.h>
#include <cstddef>

#define H 128

typedef unsigned short ushort_t;
typedef unsigned char uchar_t;
typedef __attribute__((ext_vector_type(8))) short short8;
typedef __attribute__((ext_vector_type(4))) float floatx4;
typedef __attribute__((ext_vector_type(2))) float floatx2;

// ---------------- helpers ----------------
__device__ __forceinline__ unsigned fkey(float f){
    unsigned u = __float_as_uint(f);
    return (u & 0x80000000u) ? ~u : (u | 0x80000000u);
}
__device__ __forceinline__ float funkey(unsigned k){
    unsigned u = (k & 0x80000000u) ? (k ^ 0x80000000u) : ~k;
    return __uint_as_float(u);
}
__device__ __forceinline__ ushort_t f2bf(float f){
    unsigned u = __float_as_uint(f);
    u += 0x7fffu + ((u >> 16) & 1u);      // round-to-nearest-even
    return (ushort_t)(u >> 16);
}
__device__ __forceinline__ float bf2f(ushort_t h){
    return __uint_as_float(((unsigned)h) << 16);
}
__device__ __forceinline__ uchar_t f2fp8(float v){
    int p = __builtin_amdgcn_cvt_pk_fp8_f32(v, v, 0, false);
    return (uchar_t)(p & 0xff);
}
// async global -> LDS, 16B per lane. LDS dest = wave-uniform base + lane*16.
__device__ __forceinline__ void gll16(const void* g, void* l){
    __builtin_amdgcn_global_load_lds(
        (const __attribute__((address_space(1))) unsigned int*)g,
        (__attribute__((address_space(3))) unsigned int*)l, 16, 0, 0);
}
// accumulate 8 fp8 (one int2) into 8 fp32 with weight
__device__ __forceinline__ void acc8f8(float* a, int2 u, float w){
    floatx2 p;
    p = __builtin_amdgcn_cvt_pk_f32_fp8(u.x, false); a[0] += w*p.x; a[1] += w*p.y;
    p = __builtin_amdgcn_cvt_pk_f32_fp8(u.x, true);  a[2] += w*p.x; a[3] += w*p.y;
    p = __builtin_amdgcn_cvt_pk_f32_fp8(u.y, false); a[4] += w*p.x; a[5] += w*p.y;
    p = __builtin_amdgcn_cvt_pk_f32_fp8(u.y, true);  a[6] += w*p.x; a[7] += w*p.y;
}

// ---------------- fused embeddings (bf16 states + fp8 shadows) ---------------
// blocks [0, nbP): place side; rest: trans side.
__global__ __launch_bounds__(256) void k_embed2(
    const float* __restrict__ pf, const float* __restrict__ Wpe,
    const float* __restrict__ bpe,
    const float* __restrict__ tf, const float* __restrict__ Wte,
    const float* __restrict__ bte,
    ushort_t* __restrict__ outP, uchar_t* __restrict__ xP,
    ushort_t* __restrict__ outT, uchar_t* __restrict__ xT,
    int P, int T, int nbP)
{
    int tid = threadIdx.x;
    if ((int)blockIdx.x < nbP){
        int idx = blockIdx.x*256 + tid;
        if (idx >= P*32) return;
        int p = idx >> 5, q = (idx & 31) << 2;
        float v = pf[p];
        float4 w = *(const float4*)(Wpe + q);
        float4 b = *(const float4*)(bpe + q);
        float v0 = v*w.x + b.x, v1 = v*w.y + b.y, v2 = v*w.z + b.z, v3 = v*w.w + b.w;
        ushort4 o;
        o.x = f2bf(v0); o.y = f2bf(v1); o.z = f2bf(v2); o.w = f2bf(v3);
        *(ushort4*)(outP + (size_t)p*H + q) = o;
        int pk = __builtin_amdgcn_cvt_pk_fp8_f32(v0, v1, 0, false);
        pk = __builtin_amdgcn_cvt_pk_fp8_f32(v2, v3, pk, true);
        *(int*)(xP + (size_t)p*H + q) = pk;
    } else {
        __shared__ float Wl[8*H];
        __shared__ float Bl[H];
        #pragma unroll
        for (int t = 0; t < 4; t++) Wl[tid + t*256] = Wte[tid + t*256];
        if (tid < H) Bl[tid] = bte[tid];
        __syncthreads();
        int idx = (blockIdx.x - nbP)*256 + tid;
        if (idx >= T*32) return;
        int t = idx >> 5, q = (idx & 31) << 2;
        float4 acc = *(float4*)(&Bl[q]);
        #pragma unroll
        for (int k = 0; k < 8; k++){
            float s = tf[(size_t)t*8 + k];
            float4 w = *(float4*)(&Wl[k*H + q]);
            acc.x += s*w.x; acc.y += s*w.y; acc.z += s*w.z; acc.w += s*w.w;
        }
        ushort4 o;
        o.x = f2bf(acc.x); o.y = f2bf(acc.y); o.z = f2bf(acc.z); o.w = f2bf(acc.w);
        *(ushort4*)(outT + (size_t)t*H + q) = o;
        int pk = __builtin_amdgcn_cvt_pk_fp8_f32(acc.x, acc.y, 0, false);
        pk = __builtin_amdgcn_cvt_pk_fp8_f32(acc.z, acc.w, pk, true);
        *(int*)(xT + (size_t)t*H + q) = pk;
    }
}

// prefix embedding + zero mean shadow copies + softmax slots + Sp shards
__global__ void k_init_small(const float* __restrict__ pe, int plen,
                             const float* __restrict__ Wpr, const float* __restrict__ bpr,
                             float* __restrict__ prefix, float* __restrict__ meanPsh,
                             float* __restrict__ meanTsh, float* __restrict__ slots,
                             float* __restrict__ SpSh)
{
    int c = threadIdx.x;  // 128 threads
    float a = bpr[c];
    for (int k = 0; k < plen; k++) a += pe[k]*Wpr[k*H + c];
    prefix[c] = a;
    for (int i = c; i < 4096; i += 128){ meanPsh[i] = 0.f; meanTsh[i] = 0.f; }
    for (int i = c; i < 192; i += 128) SpSh[i] = 0.f;
    if (c < 16) slots[c] = 0.f;   // fkey-space 0 == -inf
}

// ---------------- combined weight prep: A1-half + folded Wc ------------------
__global__ __launch_bounds__(256) void k_wprep2(
    const float* __restrict__ p2t_W, const float* __restrict__ t2p_W,
    const float* __restrict__ tu_W,  const float* __restrict__ pu_W,
    ushort_t* __restrict__ WT, int total)   // total = L*32768
{
    int e = blockIdx.x*256 + threadIdx.x;
    if (e >= total) return;
    int l = e / 32768, oo = e - l*32768;
    int side = oo >> 14, o2 = oo & 16383;
    int n = o2 >> 7, k = o2 & 127;
    const float* A  = side ? (t2p_W + (size_t)l*16384) : (p2t_W + (size_t)l*16384);
    const float* Bm = side ? (pu_W  + (size_t)l*32768) : (tu_W  + (size_t)l*32768);
    ushort_t* dst = WT + (size_t)l*65536 + (size_t)side*32768 + n*256;
    dst[k] = f2bf(Bm[(size_t)k*H + n]);                  // Wtop half
    const float* Ar = A + (size_t)k*H;
    const float* Bc = Bm + (size_t)128*H + n;
    float s = 0.f;
    #pragma unroll 4
    for (int j = 0; j < 128; j++) s += Ar[j] * Bc[(size_t)j*H];
    dst[128 + k] = f2bf(s);                              // folded Wc half
}

// ---------------- folded small vectors: wv, bc, c0 ---------------------------
__global__ __launch_bounds__(128) void k_wsmall(
    const float* __restrict__ p2t_W, const float* __restrict__ t2p_W,
    const float* __restrict__ tu_W,  const float* __restrict__ pu_W,
    const float* __restrict__ p2t_b, const float* __restrict__ t2p_b,
    const float* __restrict__ ta_W,  const float* __restrict__ ta_b,
    const float* __restrict__ pa_W,  const float* __restrict__ pa_b,
    float* __restrict__ wv, float* __restrict__ c0v, float* __restrict__ bcv)
{
    int b = blockIdx.x, l = b >> 1, side = b & 1;
    const float* A  = side ? (t2p_W + (size_t)l*16384) : (p2t_W + (size_t)l*16384);
    const float* Bm = side ? (pu_W  + (size_t)l*32768) : (tu_W  + (size_t)l*32768);
    const float* ab = side ? (t2p_b + (size_t)l*H) : (p2t_b + (size_t)l*H);
    const float* av = side ? (pa_W  + (size_t)l*H) : (ta_W  + (size_t)l*H);
    float asc       = side ? pa_b[l] : ta_b[l];
    int tid = threadIdx.x;
    int o = (l*2 + side)*H;
    float s = 0.f;
    for (int n = 0; n < 128; n++) s += A[(size_t)tid*H + n] * av[n];
    wv[o + tid] = s;
    float s2 = 0.f;
    for (int j = 0; j < 128; j++) s2 += ab[j] * Bm[(size_t)(128+j)*H + tid];
    bcv[o + tid] = s2;
    if (tid == 0){
        float c = 0.f;
        for (int n = 0; n < 128; n++) c += ab[n]*av[n];
        c0v[l*2 + side] = c + asc;
    }
}

// ---------------- CSR build ----------------
__global__ __launch_bounds__(256) void k_zero_ints(int* __restrict__ p, int n)
{
    int i = blockIdx.x*256 + threadIdx.x;
    int stride = gridDim.x*256;
    for (; i < n; i += stride) p[i] = 0;
}

__global__ __launch_bounds__(256) void k_hist2(
    const int* __restrict__ preD, const int* __restrict__ postD, int E,
    int* __restrict__ cntPre, int* __restrict__ cntPost,
    int* __restrict__ rankPre, int* __restrict__ rankPost)
{
    int i = blockIdx.x*256 + threadIdx.x;
    int stride = gridDim.x*256;
    for (; i < E; i += stride){
        rankPre[i] = atomicAdd(&cntPre[preD[i]], 1);
        rankPost[i] = atomicAdd(&cntPost[postD[i]], 1);
    }
}

__global__ __launch_bounds__(256) void k_scan_part(
    const int* __restrict__ cnt, int N, int* __restrict__ bsum)
{
    __shared__ int wsum[4];
    int tid = threadIdx.x, lane = tid & 63, wid = tid >> 6;
    int base = blockIdx.x*1024 + tid*4;
    int4 v = make_int4(0,0,0,0);
    if (base + 3 < N) v = *(const int4*)(cnt + base);
    else {
        if (base+0 < N) v.x = cnt[base+0];
        if (base+1 < N) v.y = cnt[base+1];
        if (base+2 < N) v.z = cnt[base+2];
    }
    int s = v.x + v.y + v.z + v.w;
    #pragma unroll
    for (int o = 1; o < 64; o <<= 1) s += __shfl_xor(s, o);
    if (lane == 0) wsum[wid] = s;
    __syncthreads();
    if (tid == 0) bsum[blockIdx.x] = wsum[0] + wsum[1] + wsum[2] + wsum[3];
}

__global__ __launch_bounds__(256) void k_scan_bsum(int* __restrict__ bsum, int nb)
{
    __shared__ int wsum[4];
    int tid = threadIdx.x, lane = tid & 63, wid = tid >> 6;
    int x = (tid < nb) ? bsum[tid] : 0;
    int inc = x;
    #pragma unroll
    for (int o = 1; o < 64; o <<= 1){
        int u = __shfl_up(inc, o);
        if (lane >= o) inc += u;
    }
    if (lane == 63) wsum[wid] = inc;
    __syncthreads();
    int woff = 0;
    if (wid > 0) woff += wsum[0];
    if (wid > 1) woff += wsum[1];
    if (wid > 2) woff += wsum[2];
    if (tid < nb) bsum[tid] = woff + inc - x;
}

__global__ __launch_bounds__(256) void k_scan_final(
    const int* __restrict__ cnt, int N, const int* __restrict__ bsum,
    int* __restrict__ rp, int E)
{
    __shared__ int wsum[4];
    int tid = threadIdx.x, lane = tid & 63, wid = tid >> 6;
    int base = blockIdx.x*1024 + tid*4;
    int4 v = make_int4(0,0,0,0);
    if (base + 3 < N) v = *(const int4*)(cnt + base);
    else {
        if (base+0 < N) v.x = cnt[base+0];
        if (base+1 < N) v.y = cnt[base+1];
        if (base+2 < N) v.z = cnt[base+2];
    }
    int t0 = v.x, t1 = t0 + v.y, t2 = t1 + v.z, t3 = t2 + v.w;
    int inc = t3;
    #pragma unroll
    for (int o = 1; o < 64; o <<= 1){
        int u = __shfl_up(inc, o);
        if (lane >= o) inc += u;
    }
    if (lane == 63) wsum[wid] = inc;
    __syncthreads();
    int woff = 0;
    if (wid > 0) woff += wsum[0];
    if (wid > 1) woff += wsum[1];
    if (wid > 2) woff += wsum[2];
    int off = bsum[blockIdx.x] + woff + inc - t3;
    if (base+0 < N) rp[base+0] = off;
    if (base+1 < N) rp[base+1] = off + t0;
    if (base+2 < N) rp[base+2] = off + t1;
    if (base+3 < N) rp[base+3] = off + t2;
    if (blockIdx.x == 0 && tid == 0) rp[N] = E;
}

__global__ __launch_bounds__(256) void k_fill2(
    const int* __restrict__ preS, const int* __restrict__ preD,
    const int* __restrict__ postS, const int* __restrict__ postD, int E,
    const int* __restrict__ rpPre, const int* __restrict__ rankPre, int* __restrict__ csrPre,
    const int* __restrict__ rpPost, const int* __restrict__ rankPost, int* __restrict__ csrPost)
{
    int i = blockIdx.x*256 + threadIdx.x;
    int stride = gridDim.x*256;
    for (; i < E; i += stride){
        csrPre[rpPre[preD[i]] + rankPre[i]] = preS[i];
        csrPost[rpPost[postD[i]] + rankPost[i]] = postS[i];
    }
}

// ---------------- dual-side score GEMV: y[r] = h[r].wv + c0, fused max -------
__global__ __launch_bounds__(256) void k_gemv2(
    const ushort_t* __restrict__ Ap, int P,
    const ushort_t* __restrict__ At, int T,
    const float* __restrict__ wvA, const float* __restrict__ wvB,
    const float* __restrict__ c0v, int c0iA, int c0iB,
    float* __restrict__ yA, float* __restrict__ yB,
    unsigned* __restrict__ MkA, unsigned* __restrict__ MkB)
{
    __shared__ float wm[4];
    int half = gridDim.x >> 1;
    int side = (blockIdx.x >= half);
    const ushort_t* A = side ? At : Ap;
    int M = side ? T : P;
    const float* wv = side ? wvB : wvA;
    float c0 = c0v[side ? c0iB : c0iA];
    float* y = side ? yB : yA;
    unsigned* Mk = side ? MkB : MkA;
    int b = side ? (blockIdx.x - half) : blockIdx.x;

    int tid = threadIdx.x, lane = tid & 63, wid = tid >> 6;
    int g = tid >> 4, gl = tid & 15;
    float w8[8];
    #pragma unroll
    for (int i = 0; i < 8; i++) w8[i] = wv[gl*8 + i];
    int stride = half*16;
    float lmax = -3.402823466e38f;
    for (int r = b*16 + g; r < M; r += stride){
        short8 u = *(const short8*)(A + (size_t)r*H + gl*8);
        float s = 0.f;
        #pragma unroll
        for (int i = 0; i < 8; i++) s += bf2f((ushort_t)u[i]) * w8[i];
        s += __shfl_xor(s, 1); s += __shfl_xor(s, 2);
        s += __shfl_xor(s, 4); s += __shfl_xor(s, 8);
        s += c0;
        if (gl == 0) y[r] = s;
        lmax = fmaxf(lmax, s);
    }
    #pragma unroll
    for (int o = 1; o < 64; o <<= 1) lmax = fmaxf(lmax, __shfl_xor(lmax, o));
    if (lane == 0) wm[wid] = lmax;
    __syncthreads();
    if (tid == 0){
        float m = fmaxf(fmaxf(wm[0], wm[1]), fmaxf(wm[2], wm[3]));
        atomicMax(Mk, fkey(m));
    }
}

// ---------------- edge weights in CSR order + sharded denominators -----------
// ew[j] = exp(y[csr[j]] - M), sequential/prefetchable (R7/R10-validated: the
// inline-expf gather variant cost +43 µs/dispatch from y-line overfetch).
// Block sums go to 32-way SpSh shards (R6 atomic lesson).
__global__ __launch_bounds__(256) void k_ew2(
    const int* __restrict__ csrPre, const int* __restrict__ csrPost, int E,
    const float* __restrict__ yA, const float* __restrict__ yB,
    const unsigned* __restrict__ MkA, const unsigned* __restrict__ MkB,
    float* __restrict__ ewA, float* __restrict__ ewB,
    float* __restrict__ SpShl)
{
    __shared__ float red[4];
    int half = gridDim.x >> 1;
    int side = (blockIdx.x >= half);
    const int* csr = side ? csrPost : csrPre;
    const float* y = side ? yB : yA;
    float Mv = funkey((side ? MkB : MkA)[0]);
    float* ew = side ? ewB : ewA;
    int b = side ? (blockIdx.x - half) : blockIdx.x;

    int tid = threadIdx.x, lane = tid & 63, wid = tid >> 6;
    int gid = b*256 + tid, stride = half*256;
    float ls = 0.f;
    for (int j = gid; j < E; j += stride){
        float w = expf(y[csr[j]] - Mv);
        ew[j] = w;
        ls += w;
    }
    #pragma unroll
    for (int o = 1; o < 64; o <<= 1) ls += __shfl_xor(ls, o);
    if (lane == 0) red[wid] = ls;
    __syncthreads();
    if (tid == 0)
        atomicAdd(&SpShl[side*32 + (blockIdx.x & 31)],
                  red[0] + red[1] + red[2] + red[3]);
}

// ---------------- dual-side CSR gather of fp8 rows + sdeg --------------------
// G[r] = sum_e ew[j] * X[csr[j]]  (UNNORMALIZED);  sdeg[r] = sum ew.
__global__ __launch_bounds__(256) void k_gather2(
    const int* __restrict__ rpPre, const int* __restrict__ csrPre, int T,
    const int* __restrict__ rpPost, const int* __restrict__ csrPost, int P,
    const float* __restrict__ ewA, const float* __restrict__ ewB,
    const uchar_t* __restrict__ XP, const uchar_t* __restrict__ XT,
    ushort_t* __restrict__ GbA, ushort_t* __restrict__ GbB,
    float* __restrict__ sdegA, float* __restrict__ sdegB)
{
    int nbT = (T + 15) >> 4;
    int side = (blockIdx.x >= nbT);
    const int* rp   = side ? rpPost : rpPre;
    const int* csr  = side ? csrPost : csrPre;
    const float* ew = side ? ewB : ewA;
    const uchar_t* X = side ? XT : XP;
    ushort_t* G     = side ? GbB : GbA;
    float* sdeg     = side ? sdegB : sdegA;
    int Nrow        = side ? P : T;
    int b = side ? (blockIdx.x - nbT) : blockIdx.x;

    int tid = threadIdx.x;
    int g = tid >> 4, gl = tid & 15;          // 16 groups x 16 lanes
    int r = b*16 + g;
    if (r >= Nrow) return;
    int j0 = rp[r], j1 = rp[r+1];
    const int2* X8 = (const int2*)X;          // fp8 row = 16 int2 (128 fp8)
    float a[8] = {0.f,0.f,0.f,0.f,0.f,0.f,0.f,0.f};
    float se = 0.f;
    int j = j0;
    for (; j + 1 < j1; j += 2){
        int s0 = csr[j], s1 = csr[j+1];
        float e0 = ew[j], e1 = ew[j+1];
        int2 u0 = X8[(size_t)s0*16 + gl];
        int2 u1 = X8[(size_t)s1*16 + gl];
        se += e0 + e1;
        acc8f8(a, u0, e0);
        acc8f8(a, u1, e1);
    }
    if (j < j1){
        int s0 = csr[j];
        float e0 = ew[j];
        int2 u0 = X8[(size_t)s0*16 + gl];
        se += e0;
        acc8f8(a, u0, e0);
    }
    int4 o;
    o.x = (int)((((unsigned)f2bf(a[1])) << 16) | (unsigned)f2bf(a[0]));
    o.y = (int)((((unsigned)f2bf(a[3])) << 16) | (unsigned)f2bf(a[2]));
    o.z = (int)((((unsigned)f2bf(a[5])) << 16) | (unsigned)f2bf(a[4]));
    o.w = (int)((((unsigned)f2bf(a[7])) << 16) | (unsigned)f2bf(a[6]));
    ((int4*)G)[(size_t)r*16 + gl] = o;
    if (gl == 0) sdeg[r] = se;
}

// ---------------- dual-side update GEMM --------------------------------------
// out = relu(A1 + A1@Wtop + invS*(G@Wc + sdeg*bc) + b)   [IN-PLACE: out == A1]
// 4-buffer LDS ring, 3-DEEP prefetch (~2 iterations of HBM-latency cover vs
// ~1 for the old 3-buffer/2-deep; iteration ~700cy vs ~900cy HBM latency).
// WAR distance unchanged: stage(t+3) overwrites tile t-1's buffer, one
// barrier after its reads completed. Counted vmcnt (newer ops at wait for
// stage(t+1) = 2*(t+2 alive) + 1 sdeg + 16*STORE + 2*(t+3 alive)):
// STORE 21/19/17, no-store 5/3/1; prologue 4/2/0.
// invS = 1/sum(32 Sp shards). STORE=false: colsum into 32 shadow copies.
template<bool STORE>
__global__ __launch_bounds__(256, 4) void k_up2(
    ushort_t* trans_h, ushort_t* place_h,
    const ushort_t* __restrict__ GbA, const ushort_t* __restrict__ GbB,
    const ushort_t* __restrict__ WTl,
    const float* __restrict__ tub, const float* __restrict__ pub,
    const float* __restrict__ bcA, const float* __restrict__ bcB,
    const float* __restrict__ SpShl,        // [64]: side0 0..31, side1 32..63
    const float* __restrict__ sdegA, const float* __restrict__ sdegB,
    uchar_t* __restrict__ XT, uchar_t* __restrict__ XP,
    int T, int P, int gridT, int gridP,
    float* __restrict__ meanTsh, float* __restrict__ meanPsh)
{
    __shared__ __align__(16) char As[4*8192];   // 4 x (A1 4KB | A2 4KB)
    __shared__ float csum[H];
    int side = (blockIdx.x >= gridT);
    ushort_t* A1        = side ? place_h : trans_h;
    const ushort_t* A2  = side ? GbB : GbA;
    const ushort_t* WT  = WTl + (side ? 32768 : 0);
    const float* bias   = side ? pub : tub;
    const float* bcp    = side ? bcB : bcA;
    const float* sdeg   = side ? sdegB : sdegA;
    uchar_t* outF8      = side ? XP : XT;
    int M               = side ? P : T;
    int G               = side ? gridP : gridT;
    int t0              = side ? (blockIdx.x - gridT) : blockIdx.x;
    float* colsum       = side ? meanPsh : meanTsh;
    float Sv = 0.f;
    {
        const float* sp = SpShl + (side ? 32 : 0);
        #pragma unroll
        for (int i = 0; i < 32; i++) Sv += sp[i];
    }
    float invS = 1.f / Sv;

    int tid = threadIdx.x;
    int lane = tid & 63, wid = tid >> 6;
    int quad = lane >> 4, l15 = lane & 15;
    int strip = wid*32;
    short8 bfr1[2][4], bfr2[2][4];
    float bcol[2], bc2[2];
    #pragma unroll
    for (int j = 0; j < 2; j++){
        int col = strip + j*16 + l15;
        #pragma unroll
        for (int kk = 0; kk < 4; kk++){
            bfr1[j][kk] = *(const short8*)(WT + (size_t)col*256 + kk*32 + quad*8);
            bfr2[j][kk] = *(const short8*)(WT + (size_t)col*256 + 128 + kk*32 + quad*8);
        }
        bcol[j] = bias[col];
        bc2[j]  = bcp[col];
    }
    // identity B-fragments: transpose the wave's A1 fragment window into C-layout
    short8 If0, If1;
    #pragma unroll
    for (int e = 0; e < 8; e++){
        int kloc = quad*8 + e;
        If0[e] = (kloc == l15)      ? (short)0x3F80 : (short)0;
        If1[e] = (kloc == l15 + 16) ? (short)0x3F80 : (short)0;
    }
    if constexpr (!STORE){ if (tid < H) csum[tid] = 0.f; }
    float cs[2] = {0.f, 0.f};

    int tiles = (M + 15) >> 4;
    if (t0 >= tiles) return;
    int srow = tid >> 4;
    int su = (tid & 15) ^ srow;
    const ushort_t* g1b = A1 + (size_t)srow*H + su*8;
    const ushort_t* g2b = A2 + (size_t)srow*H + su*8;
    char* AsB = As;

    #define STAGE_UP(bo, t) do { \
        gll16(g1b + (size_t)(t)*(16*H), AsB + (bo) + (wid<<10)); \
        gll16(g2b + (size_t)(t)*(16*H), AsB + (bo) + 4096 + (wid<<10)); \
    } while(0)

    STAGE_UP(0, t0);
    {
        int t1p = t0 + G, t2p = t0 + 2*G;
        if (t1p < tiles) STAGE_UP(8192, t1p);
        if (t2p < tiles) STAGE_UP(16384, t2p);
        if (t2p < tiles)      asm volatile("s_waitcnt vmcnt(4)\ns_barrier" ::: "memory");
        else if (t1p < tiles) asm volatile("s_waitcnt vmcnt(2)\ns_barrier" ::: "memory");
        else                  asm volatile("s_waitcnt vmcnt(0)\ns_barrier" ::: "memory");
    }

    int t = t0, bo = 0;
    for (;;){
        const char* rb = AsB + bo;
        int row0 = t << 4;
        float4 sd4 = *(const float4*)(sdeg + row0 + quad*4);
        float sdv[4] = {sd4.x, sd4.y, sd4.z, sd4.w};
        short8 a1f[4], a2f[4];
        #pragma unroll
        for (int kk = 0; kk < 4; kk++){
            int sw = ((((kk<<2)+quad) ^ l15) << 4);
            a1f[kk] = *(const short8*)(rb + (l15<<8) + sw);
            a2f[kk] = *(const short8*)(rb + 4096 + (l15<<8) + sw);
        }
        short8 ares = *(const short8*)(rb + (l15<<8) + ((((wid<<2)+quad) ^ l15) << 4));
        floatx4 acc1[2], acc2[2];
        acc1[0] = __builtin_amdgcn_mfma_f32_16x16x32_bf16(ares, If0, (floatx4)0.f, 0,0,0);
        acc1[1] = __builtin_amdgcn_mfma_f32_16x16x32_bf16(ares, If1, (floatx4)0.f, 0,0,0);
        acc2[0] = (floatx4)0.f; acc2[1] = (floatx4)0.f;
        #pragma unroll
        for (int j = 0; j < 2; j++){
            #pragma unroll
            for (int kk = 0; kk < 4; kk++)
                acc1[j] = __builtin_amdgcn_mfma_f32_16x16x32_bf16(a1f[kk], bfr1[j][kk], acc1[j], 0,0,0);
            #pragma unroll
            for (int kk = 0; kk < 4; kk++)
                acc2[j] = __builtin_amdgcn_mfma_f32_16x16x32_bf16(a2f[kk], bfr2[j][kk], acc2[j], 0,0,0);
        }
        #pragma unroll
        for (int j = 0; j < 2; j++){
            int col = strip + j*16 + l15;
            #pragma unroll
            for (int rr = 0; rr < 4; rr++){
                int grow = row0 + quad*4 + rr;
                float v = acc1[j][rr] + invS*(acc2[j][rr] + sdv[rr]*bc2[j]) + bcol[j];
                v = fmaxf(v, 0.f);
                if constexpr (STORE){
                    A1[(size_t)grow*H + col] = f2bf(v);       // 8 ushort stores
                    outF8[(size_t)grow*H + col] = f2fp8(v);   // 8 byte stores
                } else {
                    cs[j] += v;
                }
            }
        }
        int tn = t + G;
        if (tn >= tiles) break;
        bool have2 = (t + 2*G) < tiles;
        bool have3 = (t + 3*G) < tiles;
        int bo3 = bo + 24576; if (bo3 >= 32768) bo3 -= 32768;
        if (have3) STAGE_UP(bo3, t + 3*G);
        if constexpr (STORE){
            if (have3)      asm volatile("s_waitcnt vmcnt(21)\ns_barrier" ::: "memory");
            else if (have2) asm volatile("s_waitcnt vmcnt(19)\ns_barrier" ::: "memory");
            else            asm volatile("s_waitcnt vmcnt(17)\ns_barrier" ::: "memory");
        } else {
            if (have3)      asm volatile("s_waitcnt vmcnt(5)\ns_barrier" ::: "memory");
            else if (have2) asm volatile("s_waitcnt vmcnt(3)\ns_barrier" ::: "memory");
            else            asm volatile("s_waitcnt vmcnt(1)\ns_barrier" ::: "memory");
        }
        t = tn; bo += 8192; if (bo >= 32768) bo = 0;
    }
    #undef STAGE_UP
    if constexpr (!STORE){
        #pragma unroll
        for (int j = 0; j < 2; j++){
            float v = cs[j];
            v += __shfl_xor(v, 16); v += __shfl_xor(v, 32);
            if (quad == 0) atomicAdd(&csum[strip + j*16 + l15], v);
        }
        __syncthreads();
        if (tid < H) atomicAdd(&colsum[((blockIdx.x & 31) << 7) + tid], csum[tid]);
    }
}

// ---------------- tiny MLP head (reduces 32 mean shadow copies) --------------
__global__ __launch_bounds__(256) void k_head(
    const float* __restrict__ meanPsh, const float* __restrict__ meanTsh,
    float invP, float invT,
    const float* __restrict__ Wpp, const float* __restrict__ bpp,
    const float* __restrict__ Wtp, const float* __restrict__ btp,
    const float* __restrict__ prefix,
    const float* __restrict__ W1, const float* __restrict__ b1,
    const float* __restrict__ W2, const float* __restrict__ b2,
    float* __restrict__ h2g)
{
    __shared__ float mp[128], mt[128];
    __shared__ float comb[384];
    __shared__ float h1s[256];
    int tid = threadIdx.x;
    if (tid < 128){
        float s = 0.f;
        for (int c = 0; c < 32; c++) s += meanPsh[(c << 7) + tid];
        mp[tid] = s;
    } else {
        int c2 = tid - 128;
        float s = 0.f;
        for (int c = 0; c < 32; c++) s += meanTsh[(c << 7) + c2];
        mt[c2] = s;
    }
    __syncthreads();
    if (tid < 128){
        float a = bpp[tid];
        for (int k = 0; k < 128; k++) a += mp[k]*invP*Wpp[k*H + tid];
        comb[tid] = a;
        comb[256 + tid] = prefix[tid];
    } else {
        int c = tid - 128;
        float a = btp[c];
        for (int k = 0; k < 128; k++) a += mt[k]*invT*Wtp[k*H + c];
        comb[128 + c] = a;
    }
    __syncthreads();
    {
        float a = b1[tid];
        for (int k = 0; k < 384; k++) a += comb[k]*W1[k*256 + tid];
        h1s[tid] = fmaxf(a, 0.f);
    }
    __syncthreads();
    if (tid < 128){
        float a = b2[tid];
        for (int k = 0; k < 256; k++) a += h1s[k]*W2[k*H + tid];
        h2g[tid] = fmaxf(a, 0.f);
    }
}

// ---------------- logits + sigmoid ----------------
__global__ __launch_bounds__(256) void k_logits(
    const float* __restrict__ h2g, const float* __restrict__ W3,
    const float* __restrict__ b3, float* __restrict__ out, int T)
{
    __shared__ float h2l[128];
    int tid = threadIdx.x;
    if (tid < 128) h2l[tid] = h2g[tid];
    __syncthreads();
    int t = blockIdx.x*256 + tid;
    if (t >= T) return;
    float a = b3[t];
    #pragma unroll 8
    for (int k = 0; k < 128; k++) a += h2l[k]*W3[(size_t)k*T + t];
    out[t] = 1.f/(1.f + expf(-a));
}

// ---------------- launch ----------------
extern "C" void kernel_launch(void* const* d_in, const int* in_sizes, int n_in,
                              void* d_out, int out_size, void* d_ws, size_t ws_size,
                              hipStream_t stream)
{
    (void)n_in; (void)out_size; (void)ws_size;
    const float* pf    = (const float*)d_in[0];
    const float* tf    = (const float*)d_in[1];
    const float* pe    = (const float*)d_in[2];
    const int*   pre   = (const int*)d_in[3];
    const int*   post  = (const int*)d_in[4];
    const float* W_pe  = (const float*)d_in[5];
    const float* b_pe  = (const float*)d_in[6];
    const float* W_te  = (const float*)d_in[7];
    const float* b_te  = (const float*)d_in[8];
    const float* W_pr  = (const float*)d_in[9];
    const float* b_pr  = (const float*)d_in[10];
    const float* p2t_W = (const float*)d_in[11];
    const float* p2t_b = (const float*)d_in[12];
    const float* t2p_W = (const float*)d_in[13];
    const float* t2p_b = (const float*)d_in[14];
    const float* pu_W  = (const float*)d_in[15];
    const float* pu_b  = (const float*)d_in[16];
    const float* tu_W  = (const float*)d_in[17];
    const float* tu_b  = (const float*)d_in[18];
    const float* pa_W  = (const float*)d_in[19];
    const float* pa_b  = (const float*)d_in[20];
    const float* ta_W  = (const float*)d_in[21];
    const float* ta_b  = (const float*)d_in[22];
    const float* W_pp  = (const float*)d_in[23];
    const float* b_pp  = (const float*)d_in[24];
    const float* W_tp  = (const float*)d_in[25];
    const float* b_tp  = (const float*)d_in[26];
    const float* W1    = (const float*)d_in[27];
    const float* b1    = (const float*)d_in[28];
    const float* W2    = (const float*)d_in[29];
    const float* b2    = (const float*)d_in[30];
    const float* W3    = (const float*)d_in[31];
    const float* b3    = (const float*)d_in[32];

    int P = in_sizes[0];
    int T = in_sizes[1] / 8;
    int E = in_sizes[3] / 2;
    int plen = in_sizes[2];
    int L = in_sizes[11] / (H*H);

    float* ws = (float*)d_ws;
    size_t fP = (size_t)P*H, fT = (size_t)T*H;
    size_t fN = (fP > fT) ? fP : fT;
    int   Nmax = (P > T) ? P : T;

    float* yA    = ws;                    // [Nmax] place-side scores
    float* yB    = yA + Nmax;             // [Nmax] trans-side scores
    float* sdegA = yB + Nmax;             // [Nmax] per-trans sum of exp
    float* sdegB = sdegA + Nmax;          // [Nmax] per-place sum of exp
    float* sc    = sdegB + Nmax;          // 16 slots (Mk at l*4+0 / l*4+2)
    float* SpSh  = sc + 16;               // [L*2*32] sharded softmax denoms
    float* meanPsh = SpSh + 192;          // [32*128] colsum shadow copies
    float* meanTsh = meanPsh + 4096;      // [32*128]
    float* prefix  = meanTsh + 4096;      // [128]
    float* h2g     = prefix + 128;        // [128]
    float* wvv  = h2g + 128;              // [L*2*128] folded score vectors
    float* c0v  = wvv + (size_t)L*256;    // [32] folded score consts (padded)
    float* bcv  = c0v + 32;               // [L*2*128] folded bias rows

    ushort_t* bh = (ushort_t*)(bcv + (size_t)L*256);
    ushort_t* place_h = bh;               // [P,128] bf16 (updated IN-PLACE)
    ushort_t* trans_h = place_h + fP;     // [T,128] bf16 (updated IN-PLACE)
    ushort_t* GbA     = trans_h + fT;     // [Nmax,128] gathered places (per trans)
    ushort_t* GbB     = GbA + fN;         // [Nmax,128] gathered transes (per place)
    ushort_t* WTb     = GbB + fN;         // L*65536 bf16 combined update weights
    uchar_t*  XP      = (uchar_t*)(WTb + (size_t)L*65536);  // [P,128] fp8 shadow
    uchar_t*  XT      = XP + fP;                             // [T,128] fp8 shadow

    int* iw = (int*)(XT + fT);
    int* cntPre  = iw;                 // [T]
    int* cntPost = cntPre + T;         // [P]
    int* rpPre   = cntPost + P;        // [T+1]
    int* rpPost  = rpPre + (T + 1);    // [P+1]
    int* csrPre  = rpPost + (P + 2);   // [E]
    int* csrPost = csrPre + E;         // [E]
    int* rankPre = csrPost + E;        // [E]
    int* rankPost= rankPre + E;        // [E]
    int* bsumA   = rankPost + E;       // [256]
    int* bsumB   = bsumA + 256;        // [256]

    // edge-weight buffers ALIAS the rank arrays (dead after k_fill2) —
    // R6/R7/R10-validated aliasing, zero footprint growth.
    float* ewA = (float*)rankPre;      // [E] edge weights, csrPre order
    float* ewB = (float*)rankPost;     // [E] edge weights, csrPost order

    const int* pre_src  = pre;          const int* pre_dst  = pre + E;
    const int* post_src = post;         const int* post_dst = post + E;

    int wtot = L*32768;
    int nbT = (T + 1023)/1024, nbP = (P + 1023)/1024;

    int tilesP = (P + 15) >> 4, tilesT = (T + 15) >> 4;
    int gridP = (tilesP + 9)/10, gridT = (tilesT + 9)/10;
    int nbTg = (T + 15) >> 4, nbPg = (P + 15) >> 4;
    int nbPemb = (P*32 + 255)/256, nbTemb = (T*32 + 255)/256;

    k_init_small<<<1, 128, 0, stream>>>(pe, plen, W_pr, b_pr, prefix,
                                        meanPsh, meanTsh, sc, SpSh);
    k_wprep2<<<(wtot + 255)/256, 256, 0, stream>>>(p2t_W, t2p_W, tu_W, pu_W, WTb, wtot);
    k_wsmall<<<L*2, 128, 0, stream>>>(p2t_W, t2p_W, tu_W, pu_W, p2t_b, t2p_b,
                                      ta_W, ta_b, pa_W, pa_b, wvv, c0v, bcv);
    k_zero_ints<<<256, 256, 0, stream>>>(iw, P + T);
    k_hist2<<<2048, 256, 0, stream>>>(pre_dst, post_dst, E,
                                      cntPre, cntPost, rankPre, rankPost);
    k_scan_part<<<nbT, 256, 0, stream>>>(cntPre, T, bsumA);
    k_scan_bsum<<<1, 256, 0, stream>>>(bsumA, nbT);
    k_scan_final<<<nbT, 256, 0, stream>>>(cntPre, T, bsumA, rpPre, E);
    k_scan_part<<<nbP, 256, 0, stream>>>(cntPost, P, bsumB);
    k_scan_bsum<<<1, 256, 0, stream>>>(bsumB, nbP);
    k_scan_final<<<nbP, 256, 0, stream>>>(cntPost, P, bsumB, rpPost, E);
    k_fill2<<<1024, 256, 0, stream>>>(pre_src, pre_dst, post_src, post_dst, E,
                                      rpPre, rankPre, csrPre,
                                      rpPost, rankPost, csrPost);

    k_embed2<<<nbPemb + nbTemb, 256, 0, stream>>>(pf, W_pe, b_pe, tf, W_te, b_te,
                                                  place_h, XP, trans_h, XT,
                                                  P, T, nbPemb);

    for (int l = 0; l < L; l++){
        const ushort_t* WTl = WTb + (size_t)l*65536;
        const float* pub  = pu_b  + (size_t)l*H;
        const float* tub  = tu_b  + (size_t)l*H;
        const float* wvA  = wvv + (size_t)(l*2 + 0)*H;
        const float* wvB  = wvv + (size_t)(l*2 + 1)*H;
        const float* bcA  = bcv + (size_t)(l*2 + 0)*H;
        const float* bcB  = bcv + (size_t)(l*2 + 1)*H;
        float* SpShl = SpSh + l*64;
        unsigned* MkA = (unsigned*)(sc + l*4 + 0);
        unsigned* MkB = (unsigned*)(sc + l*4 + 2);
        int last = (l == L-1);

        // scores -> edge weights (sequential, + sharded denoms) -> gather -> update
        k_gemv2<<<1024, 256, 0, stream>>>(place_h, P, trans_h, T, wvA, wvB,
                                          c0v, l*2 + 0, l*2 + 1, yA, yB, MkA, MkB);
        k_ew2<<<1024, 256, 0, stream>>>(csrPre, csrPost, E, yA, yB, MkA, MkB,
                                        ewA, ewB, SpShl);
        k_gather2<<<nbTg + nbPg, 256, 0, stream>>>(rpPre, csrPre, T,
                                                   rpPost, csrPost, P,
                                                   ewA, ewB, XP, XT,
                                                   GbA, GbB, sdegA, sdegB);
        if (last)
            k_up2<false><<<gridT + gridP, 256, 0, stream>>>(
                trans_h, place_h, GbA, GbB, WTl, tub, pub, bcA, bcB,
                SpShl, sdegA, sdegB, XT, XP, T, P, gridT, gridP,
                meanTsh, meanPsh);
        else
            k_up2<true><<<gridT + gridP, 256, 0, stream>>>(
                trans_h, place_h, GbA, GbB, WTl, tub, pub, bcA, bcB,
                SpShl, sdegA, sdegB, XT, XP, T, P, gridT, gridP,
                meanTsh, meanPsh);
    }

    k_head<<<1, 256, 0, stream>>>(meanPsh, meanTsh, 1.f/(float)P, 1.f/(float)T,
                                  W_pp, b_pp, W_tp, b_tp, prefix, W1, b1, W2, b2, h2g);
    k_logits<<<(T + 255)/256, 256, 0, stream>>>(h2g, W3, b3, (float*)d_out, T);
}